// Round 9
// baseline (230.042 us; speedup 1.0000x reference)
//
#include <hip/hip_runtime.h>
#include <hip/hip_bf16.h>
#include <cstddef>
#include <cstdint>

#define B_    2
#define T_    2048
#define DIM_  1024
#define H_    8
#define HD_   128
#define BT_   (B_*T_)           // 4096
#define E3_   (3*H_*HD_)        // 3072
#define F32_EPS_ 1.1920929e-07f
#define QSC_  0.17312340490667562f   // 0.12 * log2(e): softmax runs in log2 domain

typedef __attribute__((ext_vector_type(8))) short bh8_t;
typedef __attribute__((ext_vector_type(4))) float f32x4_t;
typedef __attribute__((ext_vector_type(16))) float f32x16_t;
typedef __attribute__((ext_vector_type(4))) unsigned short us4_t;

__device__ inline unsigned short bf16r(float f) {
    unsigned u = __builtin_bit_cast(unsigned, f);
    u = (u + 0x7fffu + ((u >> 16) & 1u)) >> 16;
    return (unsigned short)u;
}
__device__ inline float b2f(unsigned short u) {
    return __builtin_bit_cast(float, (unsigned)u << 16);
}
__device__ inline unsigned cvtpk(float a, float b) {
    unsigned r;
    asm("v_cvt_pk_bf16_f32 %0, %1, %2" : "=v"(r) : "v"(a), "v"(b));
    return r;
}
__device__ inline void gl16(const unsigned short* g, unsigned short* l) {
    __builtin_amdgcn_global_load_lds((const __attribute__((address_space(1))) void*)g,
                                     (__attribute__((address_space(3))) void*)l, 16, 0, 0);
}

// ---------------- K1a: per-chunk |w| partial sums ----------------
__global__ __launch_bounds__(256) void absmean1_kernel(const float* __restrict__ w, float* __restrict__ partial) {
    int blk = blockIdx.x;
    size_t off = (size_t)blk * 4096;
    __shared__ float red[256];
    int tid = threadIdx.x;
    float acc = 0.f;
    const float* p = w + off + tid*16;
    #pragma unroll
    for (int j = 0; j < 4; j++) {
        float4 v = *(const float4*)(p + j*4);
        acc += fabsf(v.x) + fabsf(v.y) + fabsf(v.z) + fabsf(v.w);
    }
    red[tid] = acc; __syncthreads();
    for (int s = 128; s > 0; s >>= 1) { if (tid < s) red[tid] += red[tid+s]; __syncthreads(); }
    if (tid == 0) partial[blk] = red[0];
}

// ---------------- K1b: finalize 4 scales ----------------
__global__ __launch_bounds__(256) void absmean2_kernel(const float* __restrict__ partial, float* __restrict__ scales) {
    int m = blockIdx.x;
    __shared__ float red[256];
    int tid = threadIdx.x;
    red[tid] = partial[m*256 + tid]; __syncthreads();
    for (int s = 128; s > 0; s >>= 1) { if (tid < s) red[tid] += red[tid+s]; __syncthreads(); }
    if (tid == 0) scales[m] = fmaxf(red[0] / (float)(DIM_*DIM_), 1e-5f);
}

// ---------------- K2: ternary-quantize weights -> bf16 {-1,0,+1} ----------------
__global__ __launch_bounds__(256) void quant_w_kernel(const float* __restrict__ w, const float* __restrict__ scales,
                                                      unsigned short* __restrict__ wq) {
    int base = (blockIdx.x * 256 + threadIdx.x) * 8;
    float s = scales[base >> 20];
    float inv = 1.f / s;
    unsigned short out[8];
    float4 v0 = *(const float4*)(w + base);
    float4 v1 = *(const float4*)(w + base + 4);
    float t[8] = {v0.x, v0.y, v0.z, v0.w, v1.x, v1.y, v1.z, v1.w};
    #pragma unroll
    for (int j = 0; j < 8; j++) {
        float r = rintf(t[j] * inv);
        r = fminf(1.f, fmaxf(-1.f, r));
        out[j] = (r == 0.f) ? 0 : (r > 0.f ? 0x3F80 : 0xBF80);
    }
    *(int4*)(wq + base) = *(const int4*)out;
}

// ---------------- K3: per-row 8-bit quant of x (bf16 out) + gate ----------------
__global__ __launch_bounds__(256) void quant_x_gate_kernel(const float* __restrict__ x, const float* __restrict__ gw,
                                                           unsigned short* __restrict__ xqb, float* __restrict__ gate) {
    int row = blockIdx.x;
    const float* xr = x + (size_t)row * DIM_;
    unsigned short* qr = xqb + (size_t)row * DIM_;
    __shared__ float red[256];
    __shared__ float x12[12];
    int tid = threadIdx.x;
    float v[4];
    float mn = 1e30f, mx = -1e30f;
    #pragma unroll
    for (int i = 0; i < 4; i++) {
        v[i] = xr[i*256 + tid];
        mn = fminf(mn, v[i]); mx = fmaxf(mx, v[i]);
    }
    red[tid] = mn; __syncthreads();
    for (int s = 128; s > 0; s >>= 1) { if (tid < s) red[tid] = fminf(red[tid], red[tid+s]); __syncthreads(); }
    mn = red[0]; __syncthreads();
    red[tid] = mx; __syncthreads();
    for (int s = 128; s > 0; s >>= 1) { if (tid < s) red[tid] = fmaxf(red[tid], red[tid+s]); __syncthreads(); }
    mx = red[0]; __syncthreads();
    float p = fmaxf(mx, 1e-5f);
    float n = fminf(mn, -1e-5f);
    #pragma unroll
    for (int i = 0; i < 4; i++) {
        int gi = i*256 + tid;
        float xv = v[i];
        float sc = (xv >= 0.f) ? p : n;
        float q = rintf(xv / sc * 127.f) / 127.f * sc;
        qr[gi] = bf16r(q);
        if (gi < 12) x12[gi] = q;
    }
    __syncthreads();
    if (tid < H_) {
        float acc = 0.f;
        #pragma unroll
        for (int f = 0; f < 12; f++) acc += x12[f] * gw[tid*12 + f];
        gate[(size_t)row * H_ + tid] = 1.f / (1.f + expf(-acc));
    }
}

// ---------------- bf16 MFMA GEMM. BM = MT*32, BN = 128, BK = 64. OBF: bf16 output ----------------
template<int MT, bool OBF>
__global__ __launch_bounds__(256) void gemm_bf16_kernel(const unsigned short* __restrict__ A,
                                                        const unsigned short* __restrict__ Bm,
                                                        const float* __restrict__ sw, int sbase,
                                                        void* __restrict__ Cv, int M, int N, int K) {
    __shared__ __align__(16) unsigned short As[MT*32*64];
    __shared__ __align__(16) unsigned short Bs[128*64];
    int bm = blockIdx.y * (MT*32), bn = blockIdx.x * 128;
    int tid = threadIdx.x;
    int w = tid >> 6, l = tid & 63;
    int wr = w >> 1, wc = w & 1;
    int lg = l >> 4, lq = l & 15;
    f32x4_t acc[MT][4];
    #pragma unroll
    for (int mt = 0; mt < MT; mt++)
        #pragma unroll
        for (int nt = 0; nt < 4; nt++) acc[mt][nt] = (f32x4_t)0.f;

    for (int k0 = 0; k0 < K; k0 += 64) {
        #pragma unroll
        for (int i = 0; i < MT; i++) {
            int ob = (i*4 + w) << 10;
            int o  = ob + (l << 4);
            int row = o >> 7;
            int lcn = ((o >> 4) & 7) ^ (row & 7);
            gl16(A + (size_t)(bm+row)*K + k0 + lcn*8, (unsigned short*)As + (ob >> 1));
        }
        #pragma unroll
        for (int i = 0; i < 4; i++) {
            int ob = (i*4 + w) << 10;
            int o  = ob + (l << 4);
            int row = o >> 7;
            int lcn = ((o >> 4) & 7) ^ (row & 7);
            gl16(Bm + (size_t)(bn+row)*K + k0 + lcn*8, (unsigned short*)Bs + (ob >> 1));
        }
        __syncthreads();
        #pragma unroll
        for (int kk = 0; kk < 2; kk++) {
            bh8_t af[MT], bf[4];
            #pragma unroll
            for (int mt = 0; mt < MT; mt++) {
                int r = wr*(MT*16) + mt*16 + lq;
                int j = kk*4 + lg;
                af[mt] = *(const bh8_t*)(As + r*64 + (((j ^ (r & 7)))<<3));
            }
            #pragma unroll
            for (int nt = 0; nt < 4; nt++) {
                int r = wc*64 + nt*16 + lq;
                int j = kk*4 + lg;
                bf[nt] = *(const bh8_t*)(Bs + r*64 + (((j ^ (r & 7)))<<3));
            }
            #pragma unroll
            for (int mt = 0; mt < MT; mt++)
                #pragma unroll
                for (int nt = 0; nt < 4; nt++)
                    acc[mt][nt] = __builtin_amdgcn_mfma_f32_16x16x32_bf16(af[mt], bf[nt], acc[mt][nt], 0, 0, 0);
        }
        __syncthreads();
    }
    #pragma unroll
    for (int nt = 0; nt < 4; nt++) {
        int col = bn + wc*64 + nt*16 + lq;
        float s = sw[sbase + (col >> 10)];
        #pragma unroll
        for (int mt = 0; mt < MT; mt++) {
            int row = bm + wr*(MT*16) + mt*16 + lg*4;
            #pragma unroll
            for (int r = 0; r < 4; r++) {
                if constexpr (OBF)
                    ((unsigned short*)Cv)[(size_t)(row + r)*N + col] = bf16r(acc[mt][nt][r] * s);
                else
                    ((float*)Cv)[(size_t)(row + r)*N + col] = acc[mt][nt][r] * s;
            }
        }
    }
}

// ---------------- K5: rmsnorm/rotary/quant from bf16 QKV (wave-per-row, shfl, no LDS) ----------------
__global__ __launch_bounds__(256) void qkv_post_kernel(const unsigned short* __restrict__ qkvb,
                                                       const float* __restrict__ ve,
                                                       const float* __restrict__ lam,
                                                       const float* __restrict__ cosb, const float* __restrict__ sinb,
                                                       unsigned short* __restrict__ Qb, unsigned short* __restrict__ Kb,
                                                       unsigned short* __restrict__ Vb) {
    int bt = blockIdx.x;
    int b = bt >> 11, t = bt & (T_ - 1);
    int w = threadIdx.x >> 6, l = threadIdx.x & 63;
    const unsigned short* base = qkvb + (size_t)bt * E3_;
    float l0 = lam[0], l1 = lam[1];
    #pragma unroll
    for (int i = 0; i < 2; i++) {
        int h = w*2 + i;
        const unsigned short* row = base + (16 + h)*HD_;
        const float* ver = ve + (size_t)bt*DIM_ + h*HD_;
        unsigned short* dst = Vb + ((size_t)(b*H_+h)*T_ + t)*HD_;
        dst[l]      = bf16r(l0*b2f(row[l])    + l1*ver[l]);
        dst[l + 64] = bf16r(l0*b2f(row[l+64]) + l1*ver[l+64]);
    }
    float cc = cosb[(size_t)t*64 + l], ss = sinb[(size_t)t*64 + l];
    #pragma unroll
    for (int i = 0; i < 4; i++) {
        int part = w*4 + i;                 // 0..15
        const unsigned short* row = base + part*HD_;
        float x1 = b2f(row[l]), x2 = b2f(row[l+64]);
        float ssq = x1*x1 + x2*x2;
        #pragma unroll
        for (int off = 1; off < 64; off <<= 1) ssq += __shfl_xor(ssq, off);
        float rms = 1.0f / sqrtf(ssq / 128.0f + F32_EPS_);
        x1 *= rms; x2 *= rms;
        float o1 = x1*cc + x2*ss;
        float o2 = -x1*ss + x2*cc;
        float mn = fminf(o1, o2), mx = fmaxf(o1, o2);
        #pragma unroll
        for (int off = 1; off < 64; off <<= 1) {
            mn = fminf(mn, __shfl_xor(mn, off));
            mx = fmaxf(mx, __shfl_xor(mx, off));
        }
        float p = fmaxf(mx, 1e-5f);
        float n = fminf(mn, -1e-5f);
        float s1 = (o1 >= 0.f) ? p : n;
        float s2 = (o2 >= 0.f) ? p : n;
        float q1 = rintf(o1 / s1 * 127.f) / 127.f * s1;
        float q2 = rintf(o2 / s2 * 127.f) / 127.f * s2;
        if (part < 8) {
            unsigned short* dst = Qb + ((size_t)(b*H_+part)*T_ + t)*HD_;
            dst[l] = bf16r(QSC_ * q1); dst[l + 64] = bf16r(QSC_ * q2);
        } else {
            unsigned short* dst = Kb + ((size_t)(b*H_+part-8)*T_ + t)*HD_;
            dst[l] = bf16r(q1); dst[l + 64] = bf16r(q2);
        }
    }
}

// ---------------- K6: transpose V (bf16): Vb[bh][t][d] -> VT[bh][d][t] ----------------
__global__ __launch_bounds__(256) void transpose_v_kernel(const unsigned short* __restrict__ Vb,
                                                          unsigned short* __restrict__ VT) {
    int tt = blockIdx.x;
    int dt = blockIdx.y;
    int bh = blockIdx.z;
    __shared__ unsigned short L[64][80];
    int tid = threadIdx.x;
    #pragma unroll
    for (int i = 0; i < 2; i++) {
        int c = tid + i*256;
        int r = c >> 3, dc = c & 7;
        int4 v = *(const int4*)(Vb + ((size_t)bh*T_ + tt*64 + r)*HD_ + dt*64 + dc*8);
        *(int4*)(&L[r][dc*8]) = v;
    }
    __syncthreads();
    #pragma unroll
    for (int i = 0; i < 2; i++) {
        int c = tid + i*256;
        int r = c >> 3, tc = c & 7;
        unsigned short tmp[8];
        #pragma unroll
        for (int jj = 0; jj < 8; jj++) tmp[jj] = L[tc*8+jj][r];
        *(int4*)(VT + ((size_t)bh*HD_ + dt*64 + r)*T_ + tt*64 + tc*8) = *(const int4*)tmp;
    }
}

// ---------------- K7: barrier-free flash attention ----------------
// One WAVE = (bh, 32-q-row tile q32, kv-chunk of <=16 subrounds of 32 keys).
// K/V read directly from global (L2-resident); LDS only as 8KB/wave epilogue scratch.
// 2560 waves in 640 blocks, all co-resident; chunked waves write bf16 partials + (m,l).
__global__ __launch_bounds__(256, 4) void attn_kernel(const unsigned short* __restrict__ Qb,
                                                      const unsigned short* __restrict__ Kb,
                                                      const unsigned short* __restrict__ VT,
                                                      const float* __restrict__ gate,
                                                      unsigned short* __restrict__ Yb,
                                                      unsigned short* __restrict__ Opart,
                                                      float* __restrict__ MLg) {
    __shared__ __align__(16) unsigned short YSm[4*4096];   // 4 waves x 8KB scratch
    int tid = threadIdx.x;
    int w = tid >> 6, l = tid & 63;
    int wid = blockIdx.x*4 + w;
    int bh = wid / 160;                        // slow index: L2 locality per head
    int g  = wid - bh*160;                     // 0..159
    int q32, c;
    if (g < 16)      { q32 = g;                          c = 0; }
    else if (g < 48) { int t = g-16; q32 = 16 + (t>>1);  c = t & 1; }
    else if (g < 96) { int t = g-48; int q3 = t/3; q32 = 32 + q3; c = t - 3*q3; }
    else             { int t = g-96; q32 = 48 + (t>>2);  c = t & 3; }
    int nc = (q32 >> 4) + 1;                   // chunks for this q-tile
    int s0 = c*16;
    int send = min(s0 + 16, q32 + 1);
    int b = bh >> 3, h = bh & 7;
    int hh = l >> 5, l5 = l & 31;
    int qg = q32*32 + l5;

    const unsigned short* Kbase = Kb + (size_t)bh*T_*HD_;
    const unsigned short* Vbase = VT + (size_t)bh*HD_*T_;
    const unsigned short* Qg = Qb + ((size_t)bh*T_ + (size_t)q32*32) * HD_;

    bh8_t qf[8];
    #pragma unroll
    for (int ks = 0; ks < 8; ks++)
        qf[ks] = *(const bh8_t*)(Qg + (size_t)l5*HD_ + ks*16 + hh*8);

    f32x16_t o0 = (f32x16_t)0.f, o1 = (f32x16_t)0.f, o2 = (f32x16_t)0.f, o3 = (f32x16_t)0.f;
    float mrun = -1e20f, lrun = 0.f;

    for (int s = s0; s < send; s++) {
        int key0 = s*32;
        // K fragments direct from global
        bh8_t kf[8];
        #pragma unroll
        for (int ks = 0; ks < 8; ks++)
            kf[ks] = *(const bh8_t*)(Kbase + (size_t)(key0 + l5)*HD_ + ks*16 + hh*8);
        f32x16_t sA = (f32x16_t)0.f;
        __builtin_amdgcn_s_setprio(1);
        #pragma unroll
        for (int ks = 0; ks < 8; ks++)
            sA = __builtin_amdgcn_mfma_f32_32x32x16_bf16(kf[ks], qf[ks], sA, 0, 0, 0);
        __builtin_amdgcn_s_setprio(0);
        if (key0 + 31 > q32*32) {              // diagonal subround only
            #pragma unroll
            for (int r = 0; r < 16; r++) {
                int key = key0 + (r & 3) + 8*(r >> 2) + 4*hh;
                if (key > qg) sA[r] = -1e30f;
            }
        }
        // online softmax, defer-max THR=8, log2 domain
        float t8[8], t4[4];
        #pragma unroll
        for (int r = 0; r < 8; r++) t8[r] = fmaxf(sA[2*r], sA[2*r+1]);
        #pragma unroll
        for (int r = 0; r < 4; r++) t4[r] = fmaxf(t8[2*r], t8[2*r+1]);
        float tm = fmaxf(fmaxf(t4[0], t4[1]), fmaxf(t4[2], t4[3]));
        tm = fmaxf(tm, __shfl_xor(tm, 32));
        if (!__all(tm - mrun <= 8.f)) {
            float mnew = fmaxf(mrun, tm);
            float scf = __builtin_amdgcn_exp2f(mrun - mnew);
            lrun *= scf;
            o0 *= scf; o1 *= scf; o2 *= scf; o3 *= scf;
            mrun = mnew;
        }
        float pp[16];
        #pragma unroll
        for (int r = 0; r < 16; r++) pp[r] = __builtin_amdgcn_exp2f(sA[r] - mrun);
        #pragma unroll
        for (int r = 0; r < 8; r++) t8[r] = pp[2*r] + pp[2*r+1];
        #pragma unroll
        for (int r = 0; r < 4; r++) t4[r] = t8[2*r] + t8[2*r+1];
        float ls = (t4[0] + t4[1]) + (t4[2] + t4[3]);
        ls += __shfl_xor(ls, 32);
        lrun += ls;
        // pack P -> bf16 B-frags via lane<->lane+32 exchange
        unsigned u0 = cvtpk(pp[0], pp[1]),   u1 = cvtpk(pp[2], pp[3]);
        unsigned u2 = cvtpk(pp[4], pp[5]),   u3 = cvtpk(pp[6], pp[7]);
        unsigned u4 = cvtpk(pp[8], pp[9]),   u5 = cvtpk(pp[10], pp[11]);
        unsigned u6 = cvtpk(pp[12], pp[13]), u7 = cvtpk(pp[14], pp[15]);
        unsigned x0 = (unsigned)__shfl_xor((int)u0, 32), x1 = (unsigned)__shfl_xor((int)u1, 32);
        unsigned x2 = (unsigned)__shfl_xor((int)u2, 32), x3 = (unsigned)__shfl_xor((int)u3, 32);
        unsigned x4 = (unsigned)__shfl_xor((int)u4, 32), x5 = (unsigned)__shfl_xor((int)u5, 32);
        unsigned x6 = (unsigned)__shfl_xor((int)u6, 32), x7 = (unsigned)__shfl_xor((int)u7, 32);
        union { bh8_t v; unsigned uu[4]; } B0, B1;
        B0.uu[0] = hh ? x2 : u0;  B0.uu[1] = hh ? x3 : u1;
        B0.uu[2] = hh ? u2 : x0;  B0.uu[3] = hh ? u3 : x1;
        B1.uu[0] = hh ? x6 : u4;  B1.uu[1] = hh ? x7 : u5;
        B1.uu[2] = hh ? u6 : x4;  B1.uu[3] = hh ? u7 : x5;
        // V^T fragments direct from global; O^T += V^T @ P^T
        bh8_t vf[8];
        #pragma unroll
        for (int dt = 0; dt < 4; dt++) {
            vf[dt*2]   = *(const bh8_t*)(Vbase + (size_t)(dt*32 + l5)*T_ + key0 + hh*8);
            vf[dt*2+1] = *(const bh8_t*)(Vbase + (size_t)(dt*32 + l5)*T_ + key0 + 16 + hh*8);
        }
        __builtin_amdgcn_s_setprio(1);
        o0 = __builtin_amdgcn_mfma_f32_32x32x16_bf16(vf[0], B0.v, o0, 0, 0, 0);
        o0 = __builtin_amdgcn_mfma_f32_32x32x16_bf16(vf[1], B1.v, o0, 0, 0, 0);
        o1 = __builtin_amdgcn_mfma_f32_32x32x16_bf16(vf[2], B0.v, o1, 0, 0, 0);
        o1 = __builtin_amdgcn_mfma_f32_32x32x16_bf16(vf[3], B1.v, o1, 0, 0, 0);
        o2 = __builtin_amdgcn_mfma_f32_32x32x16_bf16(vf[4], B0.v, o2, 0, 0, 0);
        o2 = __builtin_amdgcn_mfma_f32_32x32x16_bf16(vf[5], B1.v, o2, 0, 0, 0);
        o3 = __builtin_amdgcn_mfma_f32_32x32x16_bf16(vf[6], B0.v, o3, 0, 0, 0);
        o3 = __builtin_amdgcn_mfma_f32_32x32x16_bf16(vf[7], B1.v, o3, 0, 0, 0);
        __builtin_amdgcn_s_setprio(0);
    }

    // ---- per-wave epilogue (no block barrier; same-wave LDS deps only) ----
    f32x16_t oA[4] = {o0, o1, o2, o3};
    unsigned short* ys = YSm + w*4096;         // 32 x 128 bf16
    float inv;
    int pslot = 0;
    if (nc == 1) {
        float gv = gate[((size_t)b*T_ + (size_t)qg)*H_ + h];
        inv = gv / lrun;
    } else {
        int off_;
        if (q32 < 32)      off_ = (q32-16)*2;
        else if (q32 < 48) off_ = 32 + (q32-32)*3;
        else               off_ = 80 + (q32-48)*4;
        pslot = (off_ + c)*16 + bh;
        inv = 1.f / lrun;
        if (hh == 0) {
            MLg[(size_t)pslot*64 + l5*2]     = mrun;
            MLg[(size_t)pslot*64 + l5*2 + 1] = lrun;
        }
    }
    #pragma unroll
    for (int dt = 0; dt < 4; dt++)
        #pragma unroll
        for (int gg = 0; gg < 4; gg++) {
            unsigned short pk4[4];
            #pragma unroll
            for (int e = 0; e < 4; e++) pk4[e] = bf16r(oA[dt][gg*4+e] * inv);
            int ch = (dt*4 + gg) ^ (l5 & 7);
            *(us4_t*)(ys + (size_t)l5*128 + ch*8 + hh*4) = *(const us4_t*)pk4;
        }
    // wave-local transpose readback -> coalesced 16B stores
    if (nc == 1) {
        #pragma unroll
        for (int i = 0; i < 8; i++) {
            int idx = l + i*64;
            int r = idx >> 4, scn = idx & 15;
            int lcn = scn ^ (r & 7);
            int4 v = *(const int4*)(ys + (size_t)r*128 + scn*8);
            *(int4*)(Yb + (size_t)(b*T_ + q32*32 + r)*DIM_ + h*HD_ + lcn*8) = v;
        }
    } else {
        unsigned short* od = Opart + (size_t)pslot*4096;
        #pragma unroll
        for (int i = 0; i < 8; i++) {
            int idx = l + i*64;
            int r = idx >> 4, scn = idx & 15;
            int lcn = scn ^ (r & 7);
            int4 v = *(const int4*)(ys + (size_t)r*128 + scn*8);
            *(int4*)(od + (size_t)r*128 + lcn*8) = v;
        }
    }
}

// ---------------- K8: merge partials for q32 >= 16, gate+normalize -> Yb ----------------
__global__ __launch_bounds__(256) void attn_merge_kernel(const unsigned short* __restrict__ Opart,
                                                         const float* __restrict__ MLg,
                                                         const float* __restrict__ gate,
                                                         unsigned short* __restrict__ Yb) {
    int mblk = blockIdx.x;                  // 0..767
    int bh = mblk & 15;
    int q32 = 16 + (mblk >> 4);             // 16..63
    int nc = (q32 >> 4) + 1;                // 2..4
    int off_;
    if (q32 < 32)      off_ = (q32-16)*2;
    else if (q32 < 48) off_ = 32 + (q32-32)*3;
    else               off_ = 80 + (q32-48)*4;
    int b = bh >> 3, h = bh & 7;
    int row = threadIdx.x >> 3;             // 0..31
    int d0  = (threadIdx.x & 7) * 16;

    float mc[4], lc[4];
    float m = -1e30f;
    #pragma unroll
    for (int cc = 0; cc < 4; cc++) {
        if (cc < nc) {
            int ps = (off_ + cc)*16 + bh;
            mc[cc] = MLg[(size_t)ps*64 + row*2];
            lc[cc] = MLg[(size_t)ps*64 + row*2 + 1];
            m = fmaxf(m, mc[cc]);
        }
    }
    float num[16];
    #pragma unroll
    for (int e = 0; e < 16; e++) num[e] = 0.f;
    float den = 0.f;
    #pragma unroll
    for (int cc = 0; cc < 4; cc++) {
        if (cc < nc) {
            int ps = (off_ + cc)*16 + bh;
            float wgt = lc[cc] * __builtin_amdgcn_exp2f(mc[cc] - m);
            den += wgt;
            const unsigned short* op = Opart + (size_t)ps*4096 + row*128 + d0;
            #pragma unroll
            for (int e8 = 0; e8 < 2; e8++) {
                union { int4 v; unsigned short q[8]; } u;
                u.v = *(const int4*)(op + e8*8);
                #pragma unroll
                for (int k = 0; k < 8; k++) num[e8*8 + k] += wgt * b2f(u.q[k]);
            }
        }
    }
    float gv = gate[((size_t)b*T_ + q32*32 + row)*H_ + h];
    float s = gv / den;
    unsigned short* yd = Yb + (size_t)(b*T_ + q32*32 + row)*DIM_ + h*HD_ + d0;
    #pragma unroll
    for (int e8 = 0; e8 < 2; e8++) {
        unsigned short pk8[8];
        #pragma unroll
        for (int k = 0; k < 8; k++) pk8[k] = bf16r(num[e8*8 + k] * s);
        *(int4*)(yd + e8*8) = *(const int4*)pk8;
    }
}

extern "C" void kernel_launch(void* const* d_in, const int* in_sizes, int n_in,
                              void* d_out, int out_size, void* d_ws, size_t ws_size,
                              hipStream_t stream) {
    const float* x    = (const float*)d_in[0];
    const float* ve   = (const float*)d_in[1];
    const float* lam  = (const float*)d_in[2];
    const float* cosb = (const float*)d_in[3];
    const float* sinb = (const float*)d_in[4];
    const float* qkvo = (const float*)d_in[5];
    const float* gw   = (const float*)d_in[6];

    char* ws = (char*)d_ws;
    float* scales  = (float*)ws;
    float* partial = scales + 16;
    unsigned short* WQb  = (unsigned short*)(ws + (1<<13));           // 8 MB
    unsigned short* XQb  = WQb + (size_t)4*DIM_*DIM_;                 // 8 MB
    unsigned short* QKVb = XQb + (size_t)BT_*DIM_;                    // 24 MB (later: Yb)
    float* GT = (float*)(QKVb + (size_t)BT_*E3_);                     // 128 KB
    unsigned short* Qb = (unsigned short*)(GT + (size_t)BT_*H_);      // 8 MB
    unsigned short* Kb = Qb + (size_t)B_*H_*T_*HD_;                   // 8 MB
    unsigned short* VT = Kb + (size_t)B_*H_*T_*HD_;                   // 8 MB
    unsigned short* Vb = VT + (size_t)B_*H_*T_*HD_;                   // 8 MB
    unsigned short* Opart = Vb + (size_t)B_*H_*T_*HD_;                // 2304 x 8 KB = 18 MB
    float* MLg = (float*)(Opart + (size_t)2304*4096);                 // 0.6 MB
    unsigned short* Yb = QKVb;                                        // reuse (dead after qkv_post)

    absmean1_kernel<<<1024, 256, 0, stream>>>(qkvo, partial);
    absmean2_kernel<<<4, 256, 0, stream>>>(partial, scales);
    quant_w_kernel<<<(4*DIM_*DIM_)/(256*8), 256, 0, stream>>>(qkvo, scales, WQb);
    quant_x_gate_kernel<<<BT_, 256, 0, stream>>>(x, gw, XQb, GT);
    gemm_bf16_kernel<4, true><<<dim3(E3_/128, BT_/128), 256, 0, stream>>>(XQb, WQb, scales, 0, QKVb, BT_, E3_, DIM_);
    qkv_post_kernel<<<BT_, 256, 0, stream>>>(QKVb, ve, lam, cosb, sinb, Qb, Kb, Vb);
    transpose_v_kernel<<<dim3(T_/64, HD_/64, B_*H_), 256, 0, stream>>>(Vb, VT);
    attn_kernel<<<640, 256, 0, stream>>>(Qb, Kb, VT, GT, Yb, Opart, MLg);
    attn_merge_kernel<<<768, 256, 0, stream>>>(Opart, MLg, GT, Yb);
    gemm_bf16_kernel<2, false><<<dim3(DIM_/128, BT_/64), 256, 0, stream>>>(Yb, WQb + (size_t)3*DIM_*DIM_, scales, 3,
                                                                           (float*)d_out, BT_, DIM_, DIM_);
}

// Round 10
// 155.242 us; speedup vs baseline: 1.4818x; 1.4818x over previous
//
#include <hip/hip_runtime.h>
#include <hip/hip_bf16.h>
#include <cstddef>
#include <cstdint>

#define B_    2
#define T_    2048
#define DIM_  1024
#define H_    8
#define HD_   128
#define BT_   (B_*T_)           // 4096
#define E3_   (3*H_*HD_)        // 3072
#define F32_EPS_ 1.1920929e-07f
#define QSC_  0.17312340490667562f   // 0.12 * log2(e): softmax runs in log2 domain

typedef __attribute__((ext_vector_type(8))) short bh8_t;
typedef __attribute__((ext_vector_type(4))) float f32x4_t;
typedef __attribute__((ext_vector_type(16))) float f32x16_t;
typedef __attribute__((ext_vector_type(4))) unsigned short us4_t;

__device__ inline unsigned short bf16r(float f) {
    unsigned u = __builtin_bit_cast(unsigned, f);
    u = (u + 0x7fffu + ((u >> 16) & 1u)) >> 16;
    return (unsigned short)u;
}
__device__ inline float b2f(unsigned short u) {
    return __builtin_bit_cast(float, (unsigned)u << 16);
}
__device__ inline unsigned cvtpk(float a, float b) {
    unsigned r;
    asm("v_cvt_pk_bf16_f32 %0, %1, %2" : "=v"(r) : "v"(a), "v"(b));
    return r;
}
__device__ inline void gl16(const unsigned short* g, unsigned short* l) {
    __builtin_amdgcn_global_load_lds((const __attribute__((address_space(1))) void*)g,
                                     (__attribute__((address_space(3))) void*)l, 16, 0, 0);
}

// ---------------- K1a: per-chunk |w| partial sums ----------------
__global__ __launch_bounds__(256) void absmean1_kernel(const float* __restrict__ w, float* __restrict__ partial) {
    int blk = blockIdx.x;
    size_t off = (size_t)blk * 4096;
    __shared__ float red[256];
    int tid = threadIdx.x;
    float acc = 0.f;
    const float* p = w + off + tid*16;
    #pragma unroll
    for (int j = 0; j < 4; j++) {
        float4 v = *(const float4*)(p + j*4);
        acc += fabsf(v.x) + fabsf(v.y) + fabsf(v.z) + fabsf(v.w);
    }
    red[tid] = acc; __syncthreads();
    for (int s = 128; s > 0; s >>= 1) { if (tid < s) red[tid] += red[tid+s]; __syncthreads(); }
    if (tid == 0) partial[blk] = red[0];
}

// ---------------- K1b: finalize 4 scales ----------------
__global__ __launch_bounds__(256) void absmean2_kernel(const float* __restrict__ partial, float* __restrict__ scales) {
    int m = blockIdx.x;
    __shared__ float red[256];
    int tid = threadIdx.x;
    red[tid] = partial[m*256 + tid]; __syncthreads();
    for (int s = 128; s > 0; s >>= 1) { if (tid < s) red[tid] += red[tid+s]; __syncthreads(); }
    if (tid == 0) scales[m] = fmaxf(red[0] / (float)(DIM_*DIM_), 1e-5f);
}

// ---------------- K2: ternary-quantize weights -> bf16 {-1,0,+1} ----------------
__global__ __launch_bounds__(256) void quant_w_kernel(const float* __restrict__ w, const float* __restrict__ scales,
                                                      unsigned short* __restrict__ wq) {
    int base = (blockIdx.x * 256 + threadIdx.x) * 8;
    float s = scales[base >> 20];
    float inv = 1.f / s;
    unsigned short out[8];
    float4 v0 = *(const float4*)(w + base);
    float4 v1 = *(const float4*)(w + base + 4);
    float t[8] = {v0.x, v0.y, v0.z, v0.w, v1.x, v1.y, v1.z, v1.w};
    #pragma unroll
    for (int j = 0; j < 8; j++) {
        float r = rintf(t[j] * inv);
        r = fminf(1.f, fmaxf(-1.f, r));
        out[j] = (r == 0.f) ? 0 : (r > 0.f ? 0x3F80 : 0xBF80);
    }
    *(int4*)(wq + base) = *(const int4*)out;
}

// ---------------- K3: per-row 8-bit quant of x (bf16 out) + gate ----------------
__global__ __launch_bounds__(256) void quant_x_gate_kernel(const float* __restrict__ x, const float* __restrict__ gw,
                                                           unsigned short* __restrict__ xqb, float* __restrict__ gate) {
    int row = blockIdx.x;
    const float* xr = x + (size_t)row * DIM_;
    unsigned short* qr = xqb + (size_t)row * DIM_;
    __shared__ float red[256];
    __shared__ float x12[12];
    int tid = threadIdx.x;
    float v[4];
    float mn = 1e30f, mx = -1e30f;
    #pragma unroll
    for (int i = 0; i < 4; i++) {
        v[i] = xr[i*256 + tid];
        mn = fminf(mn, v[i]); mx = fmaxf(mx, v[i]);
    }
    red[tid] = mn; __syncthreads();
    for (int s = 128; s > 0; s >>= 1) { if (tid < s) red[tid] = fminf(red[tid], red[tid+s]); __syncthreads(); }
    mn = red[0]; __syncthreads();
    red[tid] = mx; __syncthreads();
    for (int s = 128; s > 0; s >>= 1) { if (tid < s) red[tid] = fmaxf(red[tid], red[tid+s]); __syncthreads(); }
    mx = red[0]; __syncthreads();
    float p = fmaxf(mx, 1e-5f);
    float n = fminf(mn, -1e-5f);
    #pragma unroll
    for (int i = 0; i < 4; i++) {
        int gi = i*256 + tid;
        float xv = v[i];
        float sc = (xv >= 0.f) ? p : n;
        float q = rintf(xv / sc * 127.f) / 127.f * sc;
        qr[gi] = bf16r(q);
        if (gi < 12) x12[gi] = q;
    }
    __syncthreads();
    if (tid < H_) {
        float acc = 0.f;
        #pragma unroll
        for (int f = 0; f < 12; f++) acc += x12[f] * gw[tid*12 + f];
        gate[(size_t)row * H_ + tid] = 1.f / (1.f + expf(-acc));
    }
}

// ---------------- bf16 MFMA GEMM. BM = MT*32, BN = 128, BK = 64. OBF: bf16 output ----------------
template<int MT, bool OBF>
__global__ __launch_bounds__(256) void gemm_bf16_kernel(const unsigned short* __restrict__ A,
                                                        const unsigned short* __restrict__ Bm,
                                                        const float* __restrict__ sw, int sbase,
                                                        void* __restrict__ Cv, int M, int N, int K) {
    __shared__ __align__(16) unsigned short As[MT*32*64];
    __shared__ __align__(16) unsigned short Bs[128*64];
    int bm = blockIdx.y * (MT*32), bn = blockIdx.x * 128;
    int tid = threadIdx.x;
    int w = tid >> 6, l = tid & 63;
    int wr = w >> 1, wc = w & 1;
    int lg = l >> 4, lq = l & 15;
    f32x4_t acc[MT][4];
    #pragma unroll
    for (int mt = 0; mt < MT; mt++)
        #pragma unroll
        for (int nt = 0; nt < 4; nt++) acc[mt][nt] = (f32x4_t)0.f;

    for (int k0 = 0; k0 < K; k0 += 64) {
        #pragma unroll
        for (int i = 0; i < MT; i++) {
            int ob = (i*4 + w) << 10;
            int o  = ob + (l << 4);
            int row = o >> 7;
            int lcn = ((o >> 4) & 7) ^ (row & 7);
            gl16(A + (size_t)(bm+row)*K + k0 + lcn*8, (unsigned short*)As + (ob >> 1));
        }
        #pragma unroll
        for (int i = 0; i < 4; i++) {
            int ob = (i*4 + w) << 10;
            int o  = ob + (l << 4);
            int row = o >> 7;
            int lcn = ((o >> 4) & 7) ^ (row & 7);
            gl16(Bm + (size_t)(bn+row)*K + k0 + lcn*8, (unsigned short*)Bs + (ob >> 1));
        }
        __syncthreads();
        #pragma unroll
        for (int kk = 0; kk < 2; kk++) {
            bh8_t af[MT], bf[4];
            #pragma unroll
            for (int mt = 0; mt < MT; mt++) {
                int r = wr*(MT*16) + mt*16 + lq;
                int j = kk*4 + lg;
                af[mt] = *(const bh8_t*)(As + r*64 + (((j ^ (r & 7)))<<3));
            }
            #pragma unroll
            for (int nt = 0; nt < 4; nt++) {
                int r = wc*64 + nt*16 + lq;
                int j = kk*4 + lg;
                bf[nt] = *(const bh8_t*)(Bs + r*64 + (((j ^ (r & 7)))<<3));
            }
            #pragma unroll
            for (int mt = 0; mt < MT; mt++)
                #pragma unroll
                for (int nt = 0; nt < 4; nt++)
                    acc[mt][nt] = __builtin_amdgcn_mfma_f32_16x16x32_bf16(af[mt], bf[nt], acc[mt][nt], 0, 0, 0);
        }
        __syncthreads();
    }
    #pragma unroll
    for (int nt = 0; nt < 4; nt++) {
        int col = bn + wc*64 + nt*16 + lq;
        float s = sw[sbase + (col >> 10)];
        #pragma unroll
        for (int mt = 0; mt < MT; mt++) {
            int row = bm + wr*(MT*16) + mt*16 + lg*4;
            #pragma unroll
            for (int r = 0; r < 4; r++) {
                if constexpr (OBF)
                    ((unsigned short*)Cv)[(size_t)(row + r)*N + col] = bf16r(acc[mt][nt][r] * s);
                else
                    ((float*)Cv)[(size_t)(row + r)*N + col] = acc[mt][nt][r] * s;
            }
        }
    }
}

// ---------------- K5: rmsnorm/rotary/quant from bf16 QKV (wave-per-row, shfl, no LDS) ----------------
__global__ __launch_bounds__(256) void qkv_post_kernel(const unsigned short* __restrict__ qkvb,
                                                       const float* __restrict__ ve,
                                                       const float* __restrict__ lam,
                                                       const float* __restrict__ cosb, const float* __restrict__ sinb,
                                                       unsigned short* __restrict__ Qb, unsigned short* __restrict__ Kb,
                                                       unsigned short* __restrict__ Vb) {
    int bt = blockIdx.x;
    int b = bt >> 11, t = bt & (T_ - 1);
    int w = threadIdx.x >> 6, l = threadIdx.x & 63;
    const unsigned short* base = qkvb + (size_t)bt * E3_;
    float l0 = lam[0], l1 = lam[1];
    #pragma unroll
    for (int i = 0; i < 2; i++) {
        int h = w*2 + i;
        const unsigned short* row = base + (16 + h)*HD_;
        const float* ver = ve + (size_t)bt*DIM_ + h*HD_;
        unsigned short* dst = Vb + ((size_t)(b*H_+h)*T_ + t)*HD_;
        dst[l]      = bf16r(l0*b2f(row[l])    + l1*ver[l]);
        dst[l + 64] = bf16r(l0*b2f(row[l+64]) + l1*ver[l+64]);
    }
    float cc = cosb[(size_t)t*64 + l], ss = sinb[(size_t)t*64 + l];
    #pragma unroll
    for (int i = 0; i < 4; i++) {
        int part = w*4 + i;                 // 0..15
        const unsigned short* row = base + part*HD_;
        float x1 = b2f(row[l]), x2 = b2f(row[l+64]);
        float ssq = x1*x1 + x2*x2;
        #pragma unroll
        for (int off = 1; off < 64; off <<= 1) ssq += __shfl_xor(ssq, off);
        float rms = 1.0f / sqrtf(ssq / 128.0f + F32_EPS_);
        x1 *= rms; x2 *= rms;
        float o1 = x1*cc + x2*ss;
        float o2 = -x1*ss + x2*cc;
        float mn = fminf(o1, o2), mx = fmaxf(o1, o2);
        #pragma unroll
        for (int off = 1; off < 64; off <<= 1) {
            mn = fminf(mn, __shfl_xor(mn, off));
            mx = fmaxf(mx, __shfl_xor(mx, off));
        }
        float p = fmaxf(mx, 1e-5f);
        float n = fminf(mn, -1e-5f);
        float s1 = (o1 >= 0.f) ? p : n;
        float s2 = (o2 >= 0.f) ? p : n;
        float q1 = rintf(o1 / s1 * 127.f) / 127.f * s1;
        float q2 = rintf(o2 / s2 * 127.f) / 127.f * s2;
        if (part < 8) {
            unsigned short* dst = Qb + ((size_t)(b*H_+part)*T_ + t)*HD_;
            dst[l] = bf16r(QSC_ * q1); dst[l + 64] = bf16r(QSC_ * q2);
        } else {
            unsigned short* dst = Kb + ((size_t)(b*H_+part-8)*T_ + t)*HD_;
            dst[l] = bf16r(q1); dst[l + 64] = bf16r(q2);
        }
    }
}

// ---------------- K6: transpose V (bf16): Vb[bh][t][d] -> VT[bh][d][t] ----------------
__global__ __launch_bounds__(256) void transpose_v_kernel(const unsigned short* __restrict__ Vb,
                                                          unsigned short* __restrict__ VT) {
    int tt = blockIdx.x;
    int dt = blockIdx.y;
    int bh = blockIdx.z;
    __shared__ unsigned short L[64][80];
    int tid = threadIdx.x;
    #pragma unroll
    for (int i = 0; i < 2; i++) {
        int c = tid + i*256;
        int r = c >> 3, dc = c & 7;
        int4 v = *(const int4*)(Vb + ((size_t)bh*T_ + tt*64 + r)*HD_ + dt*64 + dc*8);
        *(int4*)(&L[r][dc*8]) = v;
    }
    __syncthreads();
    #pragma unroll
    for (int i = 0; i < 2; i++) {
        int c = tid + i*256;
        int r = c >> 3, tc = c & 7;
        unsigned short tmp[8];
        #pragma unroll
        for (int jj = 0; jj < 8; jj++) tmp[jj] = L[tc*8+jj][r];
        *(int4*)(VT + ((size_t)bh*HD_ + dt*64 + r)*T_ + tt*64 + tc*8) = *(const int4*)tmp;
    }
}

// ---------------- K7: flash attention, 2-wave blocks (5 independent groups/CU), KVBLK=32, 32KB LDS ----------------
// Block = (bh, 64-q-row tile qt, kv-chunk of <=16 rounds of 32 keys). 1280 blocks, ALL co-resident.
__global__ __launch_bounds__(128) void attn_kernel(const unsigned short* __restrict__ Qb,
                                                   const unsigned short* __restrict__ Kb,
                                                   const unsigned short* __restrict__ VT,
                                                   const float* __restrict__ gate,
                                                   unsigned short* __restrict__ Yb,
                                                   unsigned short* __restrict__ Opart,
                                                   float* __restrict__ MLg) {
    __shared__ __align__(16) unsigned char SMEM[32768];   // [2] x (K 8KB + V 8KB)
    int bh  = blockIdx.x & 15;
    int idx = blockIdx.x >> 4;                  // 0..79 per bh
    int qt, c, nc;
    if (idx < 8)       { qt = idx;                           c = 0;            nc = 1; }
    else if (idx < 24) { int t = idx - 8;  qt = 8  + (t>>1); c = t & 1;        nc = 2; }
    else if (idx < 48) { int t = idx - 24; qt = 16 + t/3;    c = t - 3*(t/3);  nc = 3; }
    else               { int t = idx - 48; qt = 24 + (t>>2); c = t & 3;        nc = 4; }
    int b = bh >> 3, h = bh & 7;
    int tid = threadIdx.x;
    int w = tid >> 6, l = tid & 63;
    int hh = l >> 5, l5 = l & 31;
    int qrow = w*32 + l5;
    int qg = qt*64 + qrow;
    int qwbase = qt*64 + w*32;

    int nrt  = 2*qt + 2;                        // 32-key rounds in tile
    int j0   = c*16;
    int jend = (nrt < j0 + 16) ? nrt : (j0 + 16);

    const unsigned short* Kbase = Kb + (size_t)bh*T_*HD_;
    const unsigned short* Vbase = VT + (size_t)bh*HD_*T_;
    const unsigned short* Qg = Qb + ((size_t)bh*T_ + (size_t)qt*64) * HD_;

    bh8_t qf[8];
    #pragma unroll
    for (int ks = 0; ks < 8; ks++)
        qf[ks] = *(const bh8_t*)(Qg + (size_t)qrow*HD_ + ks*16 + hh*8);

    f32x16_t o0 = (f32x16_t)0.f, o1 = (f32x16_t)0.f, o2 = (f32x16_t)0.f, o3 = (f32x16_t)0.f;
    float mrun = -1e20f, lrun = 0.f;

    // Stage K[32][256B] (4-bit swz) + V^T[128][64B] (2-bit swz); linear LDS dest, pre-swizzled source.
#define STAGE(BI, J) { \
    unsigned short* kb_ = (unsigned short*)(SMEM + (BI)*16384); \
    unsigned short* vb_ = (unsigned short*)(SMEM + (BI)*16384 + 8192); \
    _Pragma("unroll") \
    for (int i_ = 0; i_ < 4; i_++) { \
        int ob_ = (i_*2 + w) << 10; \
        int o_  = ob_ + (l << 4); \
        int rk_ = o_ >> 8; \
        int lk_ = ((o_ >> 4) & 15) ^ (rk_ & 15); \
        gl16(Kbase + (size_t)((J)*32 + rk_)*HD_ + lk_*8, kb_ + (ob_ >> 1)); \
        int rv_ = o_ >> 6; \
        int lv_ = ((o_ >> 4) & 3) ^ (rv_ & 3); \
        gl16(Vbase + (size_t)rv_*T_ + (J)*32 + lv_*8, vb_ + (ob_ >> 1)); \
    } }

    STAGE(0, j0);
    for (int j = j0; j < jend; j++) {
        int cur = (j - j0) & 1;
        if (j + 1 < jend) {
            STAGE(cur ^ 1, j+1);
            asm volatile("s_waitcnt vmcnt(8)" ::: "memory");
        } else {
            asm volatile("s_waitcnt vmcnt(0)" ::: "memory");
        }
        __builtin_amdgcn_s_barrier();
        asm volatile("" ::: "memory");
        const unsigned short* kb = (const unsigned short*)(SMEM + cur*16384);
        const unsigned short* vb = (const unsigned short*)(SMEM + cur*16384 + 8192);
        int kvb = j*32;
        if (kvb <= qwbase + 31) {
            // S^T(32k x 32q) = K @ Q^T   (log2 domain)
            f32x16_t sA = (f32x16_t)0.f;
            int krow = l5;
            __builtin_amdgcn_s_setprio(1);
            #pragma unroll
            for (int ks = 0; ks < 8; ks++) {
                int cch = (ks*2 + hh) ^ (krow & 15);
                bh8_t kf = *(const bh8_t*)(kb + krow*128 + cch*8);
                sA = __builtin_amdgcn_mfma_f32_32x32x16_bf16(kf, qf[ks], sA, 0, 0, 0);
            }
            __builtin_amdgcn_s_setprio(0);
            if (kvb + 31 > qwbase) {            // diagonal round only
                #pragma unroll
                for (int r = 0; r < 16; r++) {
                    int key = kvb + (r & 3) + 8*(r >> 2) + 4*hh;
                    if (key > qg) sA[r] = -1e30f;
                }
            }
            // online softmax, defer-max THR=8
            float t8[8], t4[4];
            #pragma unroll
            for (int r = 0; r < 8; r++) t8[r] = fmaxf(sA[2*r], sA[2*r+1]);
            #pragma unroll
            for (int r = 0; r < 4; r++) t4[r] = fmaxf(t8[2*r], t8[2*r+1]);
            float tm = fmaxf(fmaxf(t4[0], t4[1]), fmaxf(t4[2], t4[3]));
            tm = fmaxf(tm, __shfl_xor(tm, 32));
            if (!__all(tm - mrun <= 8.f)) {
                float mnew = fmaxf(mrun, tm);
                float scf = __builtin_amdgcn_exp2f(mrun - mnew);
                lrun *= scf;
                o0 *= scf; o1 *= scf; o2 *= scf; o3 *= scf;
                mrun = mnew;
            }
            float pp[16];
            #pragma unroll
            for (int r = 0; r < 16; r++) pp[r] = __builtin_amdgcn_exp2f(sA[r] - mrun);
            #pragma unroll
            for (int r = 0; r < 8; r++) t8[r] = pp[2*r] + pp[2*r+1];
            #pragma unroll
            for (int r = 0; r < 4; r++) t4[r] = t8[2*r] + t8[2*r+1];
            float ls = (t4[0] + t4[1]) + (t4[2] + t4[3]);
            ls += __shfl_xor(ls, 32);
            lrun += ls;
            // pack P -> bf16 B-frags via lane<->lane+32 exchange
            unsigned u0 = cvtpk(pp[0], pp[1]),   u1 = cvtpk(pp[2], pp[3]);
            unsigned u2 = cvtpk(pp[4], pp[5]),   u3 = cvtpk(pp[6], pp[7]);
            unsigned u4 = cvtpk(pp[8], pp[9]),   u5 = cvtpk(pp[10], pp[11]);
            unsigned u6 = cvtpk(pp[12], pp[13]), u7 = cvtpk(pp[14], pp[15]);
            unsigned x0 = (unsigned)__shfl_xor((int)u0, 32), x1 = (unsigned)__shfl_xor((int)u1, 32);
            unsigned x2 = (unsigned)__shfl_xor((int)u2, 32), x3 = (unsigned)__shfl_xor((int)u3, 32);
            unsigned x4 = (unsigned)__shfl_xor((int)u4, 32), x5 = (unsigned)__shfl_xor((int)u5, 32);
            unsigned x6 = (unsigned)__shfl_xor((int)u6, 32), x7 = (unsigned)__shfl_xor((int)u7, 32);
            union { bh8_t v; unsigned uu[4]; } B0, B1;
            B0.uu[0] = hh ? x2 : u0;  B0.uu[1] = hh ? x3 : u1;
            B0.uu[2] = hh ? u2 : x0;  B0.uu[3] = hh ? u3 : x1;
            B1.uu[0] = hh ? x6 : u4;  B1.uu[1] = hh ? x7 : u5;
            B1.uu[2] = hh ? u6 : x4;  B1.uu[3] = hh ? u7 : x5;
            // O^T(128d x 32q) += V^T @ P^T
            __builtin_amdgcn_s_setprio(1);
#define PV_STEP(DT, OACC) { \
    int vrow = DT*32 + l5; \
    bh8_t vf0 = *(const bh8_t*)(vb + vrow*32 + (((hh) ^ (vrow & 3))<<3)); \
    OACC = __builtin_amdgcn_mfma_f32_32x32x16_bf16(vf0, B0.v, OACC, 0, 0, 0); \
    bh8_t vf1 = *(const bh8_t*)(vb + vrow*32 + (((2 + hh) ^ (vrow & 3))<<3)); \
    OACC = __builtin_amdgcn_mfma_f32_32x32x16_bf16(vf1, B1.v, OACC, 0, 0, 0); }
            PV_STEP(0, o0) PV_STEP(1, o1) PV_STEP(2, o2) PV_STEP(3, o3)
#undef PV_STEP
            __builtin_amdgcn_s_setprio(0);
        }
        asm volatile("s_waitcnt lgkmcnt(0)" ::: "memory");
        __builtin_amdgcn_s_barrier();
        asm volatile("" ::: "memory");
    }

    // ---- per-wave epilogue: transpose via own 8KB LDS slice, coalesced stores ----
    f32x16_t oA[4] = {o0, o1, o2, o3};
    unsigned short* ys = (unsigned short*)(SMEM + w*8192);     // 32 x 128 bf16
    float inv;
    int pslot = idx*16 + bh;
    if (nc == 1) {
        float gv = gate[((size_t)b*T_ + (size_t)qg)*H_ + h];
        inv = gv / lrun;
    } else {
        inv = (lrun > 0.f) ? (1.f / lrun) : 0.f;
        if (hh == 0) {
            MLg[(size_t)pslot*128 + qrow*2]     = mrun;
            MLg[(size_t)pslot*128 + qrow*2 + 1] = lrun;
        }
    }
    #pragma unroll
    for (int dt = 0; dt < 4; dt++)
        #pragma unroll
        for (int gg = 0; gg < 4; gg++) {
            unsigned short pk4[4];
            #pragma unroll
            for (int e = 0; e < 4; e++) pk4[e] = bf16r(oA[dt][gg*4+e] * inv);
            int ch = (dt*4 + gg) ^ (l5 & 7);
            *(us4_t*)(ys + (size_t)l5*128 + ch*8 + hh*4) = *(const us4_t*)pk4;
        }
    if (nc == 1) {
        #pragma unroll
        for (int i = 0; i < 8; i++) {
            int idx2 = l + i*64;
            int r = idx2 >> 4, scn = idx2 & 15;
            int lcn = scn ^ (r & 7);
            int4 v = *(const int4*)(ys + (size_t)r*128 + scn*8);
            *(int4*)(Yb + (size_t)(b*T_ + qt*64 + w*32 + r)*DIM_ + h*HD_ + lcn*8) = v;
        }
    } else {
        unsigned short* od = Opart + (size_t)pslot*8192 + (size_t)w*32*128;
        #pragma unroll
        for (int i = 0; i < 8; i++) {
            int idx2 = l + i*64;
            int r = idx2 >> 4, scn = idx2 & 15;
            int lcn = scn ^ (r & 7);
            int4 v = *(const int4*)(ys + (size_t)r*128 + scn*8);
            *(int4*)(od + (size_t)r*128 + lcn*8) = v;
        }
    }
#undef STAGE
}

// ---------------- K8: merge split-KV partials (tiles qt >= 8), gate+normalize -> Yb ----------------
__global__ __launch_bounds__(256) void attn_merge_kernel(const unsigned short* __restrict__ Opart,
                                                         const float* __restrict__ MLg,
                                                         const float* __restrict__ gate,
                                                         unsigned short* __restrict__ Yb) {
    int mblk = blockIdx.x;                  // 0..383
    int bh = mblk & 15;
    int qt = 8 + (mblk >> 4);               // 8..31
    int nc, base;
    if (qt < 16)      { nc = 2; base = 8  + (qt - 8)*2;  }
    else if (qt < 24) { nc = 3; base = 24 + (qt - 16)*3; }
    else              { nc = 4; base = 48 + (qt - 24)*4; }
    int b = bh >> 3, h = bh & 7;
    int row = threadIdx.x >> 2;             // 0..63
    int d0  = (threadIdx.x & 3) * 32;

    float mc[4], lc[4];
    float m = -1e30f;
    #pragma unroll
    for (int cc = 0; cc < 4; cc++) {
        if (cc < nc) {
            int ps = (base + cc)*16 + bh;
            mc[cc] = MLg[(size_t)ps*128 + row*2];
            lc[cc] = MLg[(size_t)ps*128 + row*2 + 1];
            m = fmaxf(m, mc[cc]);
        }
    }
    float num[32];
    #pragma unroll
    for (int e = 0; e < 32; e++) num[e] = 0.f;
    float den = 0.f;
    #pragma unroll
    for (int cc = 0; cc < 4; cc++) {
        if (cc < nc) {
            int ps = (base + cc)*16 + bh;
            float wgt = lc[cc] * __builtin_amdgcn_exp2f(mc[cc] - m);
            den += wgt;
            const unsigned short* op = Opart + (size_t)ps*8192 + row*128 + d0;
            #pragma unroll
            for (int e8 = 0; e8 < 4; e8++) {
                union { int4 v; unsigned short q[8]; } u;
                u.v = *(const int4*)(op + e8*8);
                #pragma unroll
                for (int k = 0; k < 8; k++) num[e8*8 + k] += wgt * b2f(u.q[k]);
            }
        }
    }
    float gv = gate[((size_t)b*T_ + qt*64 + row)*H_ + h];
    float s = gv / den;
    unsigned short* yd = Yb + (size_t)(b*T_ + qt*64 + row)*DIM_ + h*HD_ + d0;
    #pragma unroll
    for (int e8 = 0; e8 < 4; e8++) {
        unsigned short pk8[8];
        #pragma unroll
        for (int k = 0; k < 8; k++) pk8[k] = bf16r(num[e8*8 + k] * s);
        *(int4*)(yd + e8*8) = *(const int4*)pk8;
    }
}

extern "C" void kernel_launch(void* const* d_in, const int* in_sizes, int n_in,
                              void* d_out, int out_size, void* d_ws, size_t ws_size,
                              hipStream_t stream) {
    const float* x    = (const float*)d_in[0];
    const float* ve   = (const float*)d_in[1];
    const float* lam  = (const float*)d_in[2];
    const float* cosb = (const float*)d_in[3];
    const float* sinb = (const float*)d_in[4];
    const float* qkvo = (const float*)d_in[5];
    const float* gw   = (const float*)d_in[6];

    char* ws = (char*)d_ws;
    float* scales  = (float*)ws;
    float* partial = scales + 16;
    unsigned short* WQb  = (unsigned short*)(ws + (1<<13));           // 8 MB
    unsigned short* XQb  = WQb + (size_t)4*DIM_*DIM_;                 // 8 MB
    unsigned short* QKVb = XQb + (size_t)BT_*DIM_;                    // 24 MB (later: Yb)
    float* GT = (float*)(QKVb + (size_t)BT_*E3_);                     // 128 KB
    unsigned short* Qb = (unsigned short*)(GT + (size_t)BT_*H_);      // 8 MB
    unsigned short* Kb = Qb + (size_t)B_*H_*T_*HD_;                   // 8 MB
    unsigned short* VT = Kb + (size_t)B_*H_*T_*HD_;                   // 8 MB
    unsigned short* Vb = VT + (size_t)B_*H_*T_*HD_;                   // 8 MB
    unsigned short* Opart = Vb + (size_t)B_*H_*T_*HD_;                // 1280 x 16 KB = 20 MB
    float* MLg = (float*)(Opart + (size_t)1280*8192);                 // 640 KB
    unsigned short* Yb = QKVb;                                        // reuse (dead after qkv_post)

    absmean1_kernel<<<1024, 256, 0, stream>>>(qkvo, partial);
    absmean2_kernel<<<4, 256, 0, stream>>>(partial, scales);
    quant_w_kernel<<<(4*DIM_*DIM_)/(256*8), 256, 0, stream>>>(qkvo, scales, WQb);
    quant_x_gate_kernel<<<BT_, 256, 0, stream>>>(x, gw, XQb, GT);
    gemm_bf16_kernel<4, true><<<dim3(E3_/128, BT_/128), 256, 0, stream>>>(XQb, WQb, scales, 0, QKVb, BT_, E3_, DIM_);
    qkv_post_kernel<<<BT_, 256, 0, stream>>>(QKVb, ve, lam, cosb, sinb, Qb, Kb, Vb);
    transpose_v_kernel<<<dim3(T_/64, HD_/64, B_*H_), 256, 0, stream>>>(Vb, VT);
    attn_kernel<<<1280, 128, 0, stream>>>(Qb, Kb, VT, GT, Yb, Opart, MLg);
    attn_merge_kernel<<<384, 256, 0, stream>>>(Opart, MLg, GT, Yb);
    gemm_bf16_kernel<2, false><<<dim3(DIM_/128, BT_/64), 256, 0, stream>>>(Yb, WQb + (size_t)3*DIM_*DIM_, scales, 3,
                                                                           (float*)d_out, BT_, DIM_, DIM_);
}

// Round 11
// 148.634 us; speedup vs baseline: 1.5477x; 1.0445x over previous
//
#include <hip/hip_runtime.h>
#include <hip/hip_bf16.h>
#include <cstddef>
#include <cstdint>

#define B_    2
#define T_    2048
#define DIM_  1024
#define H_    8
#define HD_   128
#define BT_   (B_*T_)           // 4096
#define E3_   (3*H_*HD_)        // 3072
#define F32_EPS_ 1.1920929e-07f
#define QSC_  0.17312340490667562f   // 0.12 * log2(e): softmax runs in log2 domain

typedef __attribute__((ext_vector_type(8))) short bh8_t;
typedef __attribute__((ext_vector_type(4))) float f32x4_t;
typedef __attribute__((ext_vector_type(16))) float f32x16_t;
typedef __attribute__((ext_vector_type(4))) unsigned short us4_t;

__device__ inline unsigned short bf16r(float f) {
    unsigned u = __builtin_bit_cast(unsigned, f);
    u = (u + 0x7fffu + ((u >> 16) & 1u)) >> 16;
    return (unsigned short)u;
}
__device__ inline float b2f(unsigned short u) {
    return __builtin_bit_cast(float, (unsigned)u << 16);
}
__device__ inline unsigned cvtpk(float a, float b) {
    unsigned r;
    asm("v_cvt_pk_bf16_f32 %0, %1, %2" : "=v"(r) : "v"(a), "v"(b));
    return r;
}
__device__ inline void gl16(const unsigned short* g, unsigned short* l) {
    __builtin_amdgcn_global_load_lds((const __attribute__((address_space(1))) void*)g,
                                     (__attribute__((address_space(3))) void*)l, 16, 0, 0);
}

// ---------------- K1a: per-chunk |w| partial sums ----------------
__global__ __launch_bounds__(256) void absmean1_kernel(const float* __restrict__ w, float* __restrict__ partial) {
    int blk = blockIdx.x;
    size_t off = (size_t)blk * 4096;
    __shared__ float red[256];
    int tid = threadIdx.x;
    float acc = 0.f;
    const float* p = w + off + tid*16;
    #pragma unroll
    for (int j = 0; j < 4; j++) {
        float4 v = *(const float4*)(p + j*4);
        acc += fabsf(v.x) + fabsf(v.y) + fabsf(v.z) + fabsf(v.w);
    }
    red[tid] = acc; __syncthreads();
    for (int s = 128; s > 0; s >>= 1) { if (tid < s) red[tid] += red[tid+s]; __syncthreads(); }
    if (tid == 0) partial[blk] = red[0];
}

// ---------------- K1b: finalize 4 scales ----------------
__global__ __launch_bounds__(256) void absmean2_kernel(const float* __restrict__ partial, float* __restrict__ scales) {
    int m = blockIdx.x;
    __shared__ float red[256];
    int tid = threadIdx.x;
    red[tid] = partial[m*256 + tid]; __syncthreads();
    for (int s = 128; s > 0; s >>= 1) { if (tid < s) red[tid] += red[tid+s]; __syncthreads(); }
    if (tid == 0) scales[m] = fmaxf(red[0] / (float)(DIM_*DIM_), 1e-5f);
}

// ---------------- K2: ternary-quantize weights -> bf16 {-1,0,+1} ----------------
__global__ __launch_bounds__(256) void quant_w_kernel(const float* __restrict__ w, const float* __restrict__ scales,
                                                      unsigned short* __restrict__ wq) {
    int base = (blockIdx.x * 256 + threadIdx.x) * 8;
    float s = scales[base >> 20];
    float inv = 1.f / s;
    unsigned short out[8];
    float4 v0 = *(const float4*)(w + base);
    float4 v1 = *(const float4*)(w + base + 4);
    float t[8] = {v0.x, v0.y, v0.z, v0.w, v1.x, v1.y, v1.z, v1.w};
    #pragma unroll
    for (int j = 0; j < 8; j++) {
        float r = rintf(t[j] * inv);
        r = fminf(1.f, fmaxf(-1.f, r));
        out[j] = (r == 0.f) ? 0 : (r > 0.f ? 0x3F80 : 0xBF80);
    }
    *(int4*)(wq + base) = *(const int4*)out;
}

// ---------------- K3: per-row 8-bit quant of x (bf16 out) + gate ----------------
__global__ __launch_bounds__(256) void quant_x_gate_kernel(const float* __restrict__ x, const float* __restrict__ gw,
                                                           unsigned short* __restrict__ xqb, float* __restrict__ gate) {
    int row = blockIdx.x;
    const float* xr = x + (size_t)row * DIM_;
    unsigned short* qr = xqb + (size_t)row * DIM_;
    __shared__ float red[256];
    __shared__ float x12[12];
    int tid = threadIdx.x;
    float v[4];
    float mn = 1e30f, mx = -1e30f;
    #pragma unroll
    for (int i = 0; i < 4; i++) {
        v[i] = xr[i*256 + tid];
        mn = fminf(mn, v[i]); mx = fmaxf(mx, v[i]);
    }
    red[tid] = mn; __syncthreads();
    for (int s = 128; s > 0; s >>= 1) { if (tid < s) red[tid] = fminf(red[tid], red[tid+s]); __syncthreads(); }
    mn = red[0]; __syncthreads();
    red[tid] = mx; __syncthreads();
    for (int s = 128; s > 0; s >>= 1) { if (tid < s) red[tid] = fmaxf(red[tid], red[tid+s]); __syncthreads(); }
    mx = red[0]; __syncthreads();
    float p = fmaxf(mx, 1e-5f);
    float n = fminf(mn, -1e-5f);
    #pragma unroll
    for (int i = 0; i < 4; i++) {
        int gi = i*256 + tid;
        float xv = v[i];
        float sc = (xv >= 0.f) ? p : n;
        float q = rintf(xv / sc * 127.f) / 127.f * sc;
        qr[gi] = bf16r(q);
        if (gi < 12) x12[gi] = q;
    }
    __syncthreads();
    if (tid < H_) {
        float acc = 0.f;
        #pragma unroll
        for (int f = 0; f < 12; f++) acc += x12[f] * gw[tid*12 + f];
        gate[(size_t)row * H_ + tid] = 1.f / (1.f + expf(-acc));
    }
}

// ---------------- bf16 MFMA GEMM. BM = MT*32, BN = 128, BK = 64. XCD-swizzled grid ----------------
template<int MT, bool OBF>
__global__ __launch_bounds__(256) void gemm_bf16_kernel(const unsigned short* __restrict__ A,
                                                        const unsigned short* __restrict__ Bm,
                                                        const float* __restrict__ sw, int sbase,
                                                        void* __restrict__ Cv, int M, int N, int K) {
    __shared__ __align__(16) unsigned short As[MT*32*64];
    __shared__ __align__(16) unsigned short Bs[128*64];
    // XCD-aware bijective block swizzle (requires nwg % 8 == 0; true for 768 and 256)
    int nwg = gridDim.x * gridDim.y;
    int lid = blockIdx.y * gridDim.x + blockIdx.x;
    int cpx = nwg >> 3;
    int swz = (lid & 7) * cpx + (lid >> 3);
    int bx = swz % gridDim.x, by = swz / gridDim.x;
    int bm = by * (MT*32), bn = bx * 128;
    int tid = threadIdx.x;
    int w = tid >> 6, l = tid & 63;
    int wr = w >> 1, wc = w & 1;
    int lg = l >> 4, lq = l & 15;
    f32x4_t acc[MT][4];
    #pragma unroll
    for (int mt = 0; mt < MT; mt++)
        #pragma unroll
        for (int nt = 0; nt < 4; nt++) acc[mt][nt] = (f32x4_t)0.f;

    for (int k0 = 0; k0 < K; k0 += 64) {
        #pragma unroll
        for (int i = 0; i < MT; i++) {
            int ob = (i*4 + w) << 10;
            int o  = ob + (l << 4);
            int row = o >> 7;
            int lcn = ((o >> 4) & 7) ^ (row & 7);
            gl16(A + (size_t)(bm+row)*K + k0 + lcn*8, (unsigned short*)As + (ob >> 1));
        }
        #pragma unroll
        for (int i = 0; i < 4; i++) {
            int ob = (i*4 + w) << 10;
            int o  = ob + (l << 4);
            int row = o >> 7;
            int lcn = ((o >> 4) & 7) ^ (row & 7);
            gl16(Bm + (size_t)(bn+row)*K + k0 + lcn*8, (unsigned short*)Bs + (ob >> 1));
        }
        __syncthreads();
        #pragma unroll
        for (int kk = 0; kk < 2; kk++) {
            bh8_t af[MT], bf[4];
            #pragma unroll
            for (int mt = 0; mt < MT; mt++) {
                int r = wr*(MT*16) + mt*16 + lq;
                int j = kk*4 + lg;
                af[mt] = *(const bh8_t*)(As + r*64 + (((j ^ (r & 7)))<<3));
            }
            #pragma unroll
            for (int nt = 0; nt < 4; nt++) {
                int r = wc*64 + nt*16 + lq;
                int j = kk*4 + lg;
                bf[nt] = *(const bh8_t*)(Bs + r*64 + (((j ^ (r & 7)))<<3));
            }
            #pragma unroll
            for (int mt = 0; mt < MT; mt++)
                #pragma unroll
                for (int nt = 0; nt < 4; nt++)
                    acc[mt][nt] = __builtin_amdgcn_mfma_f32_16x16x32_bf16(af[mt], bf[nt], acc[mt][nt], 0, 0, 0);
        }
        __syncthreads();
    }
    #pragma unroll
    for (int nt = 0; nt < 4; nt++) {
        int col = bn + wc*64 + nt*16 + lq;
        float s = sw[sbase + (col >> 10)];
        #pragma unroll
        for (int mt = 0; mt < MT; mt++) {
            int row = bm + wr*(MT*16) + mt*16 + lg*4;
            #pragma unroll
            for (int r = 0; r < 4; r++) {
                if constexpr (OBF)
                    ((unsigned short*)Cv)[(size_t)(row + r)*N + col] = bf16r(acc[mt][nt][r] * s);
                else
                    ((float*)Cv)[(size_t)(row + r)*N + col] = acc[mt][nt][r] * s;
            }
        }
    }
}

// ---------------- K5: rmsnorm/rotary/quant from bf16 QKV (wave-per-row, shfl, no LDS) ----------------
__global__ __launch_bounds__(256) void qkv_post_kernel(const unsigned short* __restrict__ qkvb,
                                                       const float* __restrict__ ve,
                                                       const float* __restrict__ lam,
                                                       const float* __restrict__ cosb, const float* __restrict__ sinb,
                                                       unsigned short* __restrict__ Qb, unsigned short* __restrict__ Kb,
                                                       unsigned short* __restrict__ Vb) {
    int bt = blockIdx.x;
    int b = bt >> 11, t = bt & (T_ - 1);
    int w = threadIdx.x >> 6, l = threadIdx.x & 63;
    const unsigned short* base = qkvb + (size_t)bt * E3_;
    float l0 = lam[0], l1 = lam[1];
    #pragma unroll
    for (int i = 0; i < 2; i++) {
        int h = w*2 + i;
        const unsigned short* row = base + (16 + h)*HD_;
        const float* ver = ve + (size_t)bt*DIM_ + h*HD_;
        unsigned short* dst = Vb + ((size_t)(b*H_+h)*T_ + t)*HD_;
        dst[l]      = bf16r(l0*b2f(row[l])    + l1*ver[l]);
        dst[l + 64] = bf16r(l0*b2f(row[l+64]) + l1*ver[l+64]);
    }
    float cc = cosb[(size_t)t*64 + l], ss = sinb[(size_t)t*64 + l];
    #pragma unroll
    for (int i = 0; i < 4; i++) {
        int part = w*4 + i;                 // 0..15
        const unsigned short* row = base + part*HD_;
        float x1 = b2f(row[l]), x2 = b2f(row[l+64]);
        float ssq = x1*x1 + x2*x2;
        #pragma unroll
        for (int off = 1; off < 64; off <<= 1) ssq += __shfl_xor(ssq, off);
        float rms = 1.0f / sqrtf(ssq / 128.0f + F32_EPS_);
        x1 *= rms; x2 *= rms;
        float o1 = x1*cc + x2*ss;
        float o2 = -x1*ss + x2*cc;
        float mn = fminf(o1, o2), mx = fmaxf(o1, o2);
        #pragma unroll
        for (int off = 1; off < 64; off <<= 1) {
            mn = fminf(mn, __shfl_xor(mn, off));
            mx = fmaxf(mx, __shfl_xor(mx, off));
        }
        float p = fmaxf(mx, 1e-5f);
        float n = fminf(mn, -1e-5f);
        float s1 = (o1 >= 0.f) ? p : n;
        float s2 = (o2 >= 0.f) ? p : n;
        float q1 = rintf(o1 / s1 * 127.f) / 127.f * s1;
        float q2 = rintf(o2 / s2 * 127.f) / 127.f * s2;
        if (part < 8) {
            unsigned short* dst = Qb + ((size_t)(b*H_+part)*T_ + t)*HD_;
            dst[l] = bf16r(QSC_ * q1); dst[l + 64] = bf16r(QSC_ * q2);
        } else {
            unsigned short* dst = Kb + ((size_t)(b*H_+part-8)*T_ + t)*HD_;
            dst[l] = bf16r(q1); dst[l + 64] = bf16r(q2);
        }
    }
}

// ---------------- K6: transpose V (bf16): Vb[bh][t][d] -> VT[bh][d][t] ----------------
__global__ __launch_bounds__(256) void transpose_v_kernel(const unsigned short* __restrict__ Vb,
                                                          unsigned short* __restrict__ VT) {
    int tt = blockIdx.x;
    int dt = blockIdx.y;
    int bh = blockIdx.z;
    __shared__ unsigned short L[64][80];
    int tid = threadIdx.x;
    #pragma unroll
    for (int i = 0; i < 2; i++) {
        int c = tid + i*256;
        int r = c >> 3, dc = c & 7;
        int4 v = *(const int4*)(Vb + ((size_t)bh*T_ + tt*64 + r)*HD_ + dt*64 + dc*8);
        *(int4*)(&L[r][dc*8]) = v;
    }
    __syncthreads();
    #pragma unroll
    for (int i = 0; i < 2; i++) {
        int c = tid + i*256;
        int r = c >> 3, tc = c & 7;
        unsigned short tmp[8];
        #pragma unroll
        for (int jj = 0; jj < 8; jj++) tmp[jj] = L[tc*8+jj][r];
        *(int4*)(VT + ((size_t)bh*HD_ + dt*64 + r)*T_ + tt*64 + tc*8) = *(const int4*)tmp;
    }
}

// ---------------- K7: flash attention (r6 structure), XCD-swizzled bh-major work layout ----------------
// 512 blocks; XCD x gets heads {2x, 2x+1}; CU pairs get complementary qt lengths (33 rounds/CU).
__global__ __launch_bounds__(256) void attn_kernel(const unsigned short* __restrict__ Qb,
                                                   const unsigned short* __restrict__ Kb,
                                                   const unsigned short* __restrict__ VT,
                                                   const float* __restrict__ gate,
                                                   unsigned short* __restrict__ Yb) {
    __shared__ __align__(16) unsigned char SMEM[65536];   // K[2]:2x16KB | V[2]:2x16KB
    int L = blockIdx.x;
    int xcd = L & 7, n = L >> 3;               // n: 0..63 within XCD
    int bh = xcd*2 + (n & 1);
    int qi = n >> 1;                           // 0..31
    int qt = (qi < 16) ? (31 - qi) : (qi - 16);
    int b = bh >> 3, h = bh & 7;
    int tid = threadIdx.x;
    int w = tid >> 6, l = tid & 63;
    int qsub = w >> 1, qq = w & 1;
    int hh = l >> 5, l5 = l & 31;
    int qrow = qsub*32 + l5;
    int qg = qt*64 + qrow;

    const unsigned short* Kbase = Kb + (size_t)bh*T_*HD_;
    const unsigned short* Vbase = VT + (size_t)bh*HD_*T_;
    const unsigned short* Qg = Qb + ((size_t)bh*T_ + (size_t)qt*64) * HD_;

    bh8_t qf[8];
    #pragma unroll
    for (int ks = 0; ks < 8; ks++)
        qf[ks] = *(const bh8_t*)(Qg + (size_t)qrow*HD_ + ks*16 + hh*8);

    int nr = qt + 1;

    f32x16_t o0 = (f32x16_t)0.f, o1 = (f32x16_t)0.f, o2 = (f32x16_t)0.f, o3 = (f32x16_t)0.f;
    float mrun = -1e20f, lrun = 0.f;

    // K: 4-bit XOR swizzle (16-chunk rows, 2-way = free); V: 3-bit (8-chunk rows)
#define STAGE(BI, J) { \
    unsigned short* kb_ = (unsigned short*)(SMEM + (BI)*16384); \
    unsigned short* vb_ = (unsigned short*)(SMEM + 32768 + (BI)*16384); \
    _Pragma("unroll") \
    for (int i_ = 0; i_ < 4; i_++) { \
        int ob_ = (i_*4 + w) << 10; \
        int o_  = ob_ + (l << 4); \
        int rk_ = o_ >> 8; \
        int lk_ = ((o_ >> 4) & 15) ^ (rk_ & 15); \
        gl16(Kbase + (size_t)((J)*64 + rk_)*HD_ + lk_*8, kb_ + (ob_ >> 1)); \
        int rv_ = o_ >> 7; \
        int lv_ = ((o_ >> 4) & 7) ^ (rv_ & 7); \
        gl16(Vbase + (size_t)rv_*T_ + (J)*64 + lv_*8, vb_ + (ob_ >> 1)); \
    } }

    STAGE(0, 0);
    for (int j = 0; j < nr; j++) {
        if (j + 1 < nr) {
            STAGE((j+1) & 1, j+1);
            asm volatile("s_waitcnt vmcnt(8)" ::: "memory");
        } else {
            asm volatile("s_waitcnt vmcnt(0)" ::: "memory");
        }
        __builtin_amdgcn_s_barrier();
        asm volatile("" ::: "memory");
        const unsigned short* kb = (const unsigned short*)(SMEM + (j&1)*16384);
        const unsigned short* vb = (const unsigned short*)(SMEM + 32768 + (j&1)*16384);
        int kvb = j*64 + qq*32;
        if (kvb <= qt*64 + qsub*32 + 31) {
            // S^T(32k x 32q) = K_half @ Q^T   (log2 domain: Q pre-scaled by 0.12*log2e)
            f32x16_t s = (f32x16_t)0.f;
            int krow = qq*32 + l5;
            __builtin_amdgcn_s_setprio(1);
            #pragma unroll
            for (int ks = 0; ks < 8; ks++) {
                int c = (ks*2 + hh) ^ (krow & 15);
                bh8_t kf = *(const bh8_t*)(kb + krow*128 + c*8);
                s = __builtin_amdgcn_mfma_f32_32x32x16_bf16(kf, qf[ks], s, 0, 0, 0);
            }
            __builtin_amdgcn_s_setprio(0);
            if (kvb + 31 > qt*64 + qsub*32) {
                #pragma unroll
                for (int r = 0; r < 16; r++) {
                    int key = kvb + (r & 3) + 8*(r >> 2) + 4*hh;
                    if (key > qg) s[r] = -1e30f;
                }
            }
            // online softmax, defer-max THR=8 (P bounded by 2^8)
            float t8[8], t4[4];
            #pragma unroll
            for (int r = 0; r < 8; r++) t8[r] = fmaxf(s[2*r], s[2*r+1]);
            #pragma unroll
            for (int r = 0; r < 4; r++) t4[r] = fmaxf(t8[2*r], t8[2*r+1]);
            float tm = fmaxf(fmaxf(t4[0], t4[1]), fmaxf(t4[2], t4[3]));
            tm = fmaxf(tm, __shfl_xor(tm, 32));
            if (!__all(tm - mrun <= 8.f)) {
                float mnew = fmaxf(mrun, tm);
                float scf = __builtin_amdgcn_exp2f(mrun - mnew);
                lrun *= scf;
                o0 *= scf; o1 *= scf; o2 *= scf; o3 *= scf;
                mrun = mnew;
            }
            float p[16];
            #pragma unroll
            for (int r = 0; r < 16; r++) p[r] = __builtin_amdgcn_exp2f(s[r] - mrun);
            #pragma unroll
            for (int r = 0; r < 8; r++) t8[r] = p[2*r] + p[2*r+1];
            #pragma unroll
            for (int r = 0; r < 4; r++) t4[r] = t8[2*r] + t8[2*r+1];
            float ls = (t4[0] + t4[1]) + (t4[2] + t4[3]);
            ls += __shfl_xor(ls, 32);
            lrun += ls;
            // pack P -> bf16 B-frags (v_cvt_pk) via lane<->lane+32 exchange
            unsigned u0 = cvtpk(p[0], p[1]),   u1 = cvtpk(p[2], p[3]);
            unsigned u2 = cvtpk(p[4], p[5]),   u3 = cvtpk(p[6], p[7]);
            unsigned u4 = cvtpk(p[8], p[9]),   u5 = cvtpk(p[10], p[11]);
            unsigned u6 = cvtpk(p[12], p[13]), u7 = cvtpk(p[14], p[15]);
            unsigned x0 = (unsigned)__shfl_xor((int)u0, 32), x1 = (unsigned)__shfl_xor((int)u1, 32);
            unsigned x2 = (unsigned)__shfl_xor((int)u2, 32), x3 = (unsigned)__shfl_xor((int)u3, 32);
            unsigned x4 = (unsigned)__shfl_xor((int)u4, 32), x5 = (unsigned)__shfl_xor((int)u5, 32);
            unsigned x6 = (unsigned)__shfl_xor((int)u6, 32), x7 = (unsigned)__shfl_xor((int)u7, 32);
            union { bh8_t v; unsigned uu[4]; } B0, B1;
            B0.uu[0] = hh ? x2 : u0;  B0.uu[1] = hh ? x3 : u1;
            B0.uu[2] = hh ? u2 : x0;  B0.uu[3] = hh ? u3 : x1;
            B1.uu[0] = hh ? x6 : u4;  B1.uu[1] = hh ? x7 : u5;
            B1.uu[2] = hh ? u6 : x4;  B1.uu[3] = hh ? u7 : x5;
            // O^T(128d x 32q) += V^T_half @ P^T
            __builtin_amdgcn_s_setprio(1);
#define PV_STEP(DT, OACC) { \
    int vrow = DT*32 + l5; \
    bh8_t vf0 = *(const bh8_t*)(vb + vrow*64 + (((qq*4 + hh) ^ (vrow & 7))<<3)); \
    OACC = __builtin_amdgcn_mfma_f32_32x32x16_bf16(vf0, B0.v, OACC, 0, 0, 0); \
    bh8_t vf1 = *(const bh8_t*)(vb + vrow*64 + (((qq*4 + 2 + hh) ^ (vrow & 7))<<3)); \
    OACC = __builtin_amdgcn_mfma_f32_32x32x16_bf16(vf1, B1.v, OACC, 0, 0, 0); }
            PV_STEP(0, o0) PV_STEP(1, o1) PV_STEP(2, o2) PV_STEP(3, o3)
#undef PV_STEP
            __builtin_amdgcn_s_setprio(0);
        }
        asm volatile("s_waitcnt lgkmcnt(0)" ::: "memory");
        __builtin_amdgcn_s_barrier();
        asm volatile("" ::: "memory");
    }

    // ---- 2-way stream merge per qsub (LDS reuse), then epilogue ----
    f32x16_t oA[4] = {o0, o1, o2, o3};
    float* OB = (float*)SMEM;
    float* ML = (float*)(SMEM + 32768);
    unsigned short* YS = (unsigned short*)(SMEM + 33280);
    if (qq != 0) {
        float* obuf = OB + (size_t)qsub * 4096;
        #pragma unroll
        for (int dt = 0; dt < 4; dt++)
            #pragma unroll
            for (int g = 0; g < 4; g++) {
                f32x4_t v4;
                #pragma unroll
                for (int e = 0; e < 4; e++) v4[e] = oA[dt][g*4+e];
                int ch = (dt*4 + g) ^ (l & 7);
                *(f32x4_t*)(obuf + l*64 + ch*4) = v4;
            }
        if (hh == 0) {
            ML[(qsub*32 + l5)*2]     = mrun;
            ML[(qsub*32 + l5)*2 + 1] = lrun;
        }
    }
    __syncthreads();
    if (qq == 0) {
        float mb = ML[(qsub*32 + l5)*2];
        float lb = ML[(qsub*32 + l5)*2 + 1];
        float mN = fmaxf(mrun, mb);
        float fa = __builtin_amdgcn_exp2f(mrun - mN), fb = __builtin_amdgcn_exp2f(mb - mN);
        const float* obuf = OB + (size_t)qsub * 4096;
        #pragma unroll
        for (int dt = 0; dt < 4; dt++)
            #pragma unroll
            for (int g = 0; g < 4; g++) {
                int ch = (dt*4 + g) ^ (l & 7);
                f32x4_t v4 = *(const f32x4_t*)(obuf + l*64 + ch*4);
                #pragma unroll
                for (int e = 0; e < 4; e++)
                    oA[dt][g*4+e] = oA[dt][g*4+e]*fa + v4[e]*fb;
            }
        lrun = lrun*fa + lb*fb;
        float gv = gate[((size_t)b*T_ + (size_t)qg)*H_ + h];
        float inv = gv / lrun;
        #pragma unroll
        for (int dt = 0; dt < 4; dt++)
            #pragma unroll
            for (int g = 0; g < 4; g++) {
                unsigned short pk4[4];
                #pragma unroll
                for (int e = 0; e < 4; e++) pk4[e] = bf16r(oA[dt][g*4+e] * inv);
                int ch = (dt*4 + g) ^ (qrow & 7);
                *(us4_t*)(YS + (size_t)qrow*128 + ch*8 + hh*4) = *(const us4_t*)pk4;
            }
    }
    __syncthreads();
    #pragma unroll
    for (int i = 0; i < 4; i++) {
        int idx = tid + i*256;
        int r = idx >> 4, scn = idx & 15;
        int lcn = scn ^ (r & 7);
        int4 v = *(const int4*)(YS + (size_t)r*128 + scn*8);
        *(int4*)(Yb + (size_t)(b*T_ + qt*64 + r)*DIM_ + h*HD_ + lcn*8) = v;
    }
#undef STAGE
}

extern "C" void kernel_launch(void* const* d_in, const int* in_sizes, int n_in,
                              void* d_out, int out_size, void* d_ws, size_t ws_size,
                              hipStream_t stream) {
    const float* x    = (const float*)d_in[0];
    const float* ve   = (const float*)d_in[1];
    const float* lam  = (const float*)d_in[2];
    const float* cosb = (const float*)d_in[3];
    const float* sinb = (const float*)d_in[4];
    const float* qkvo = (const float*)d_in[5];
    const float* gw   = (const float*)d_in[6];

    char* ws = (char*)d_ws;
    float* scales  = (float*)ws;
    float* partial = scales + 16;
    unsigned short* WQb  = (unsigned short*)(ws + (1<<13));           // 8 MB
    unsigned short* XQb  = WQb + (size_t)4*DIM_*DIM_;                 // 8 MB
    unsigned short* QKVb = XQb + (size_t)BT_*DIM_;                    // 24 MB (later: Yb)
    float* GT = (float*)(QKVb + (size_t)BT_*E3_);                     // 128 KB
    unsigned short* Qb = (unsigned short*)(GT + (size_t)BT_*H_);      // 8 MB
    unsigned short* Kb = Qb + (size_t)B_*H_*T_*HD_;                   // 8 MB
    unsigned short* VT = Kb + (size_t)B_*H_*T_*HD_;                   // 8 MB
    unsigned short* Vb = VT + (size_t)B_*H_*T_*HD_;                   // 8 MB
    unsigned short* Yb = QKVb;                                        // reuse (dead after qkv_post)

    absmean1_kernel<<<1024, 256, 0, stream>>>(qkvo, partial);
    absmean2_kernel<<<4, 256, 0, stream>>>(partial, scales);
    quant_w_kernel<<<(4*DIM_*DIM_)/(256*8), 256, 0, stream>>>(qkvo, scales, WQb);
    quant_x_gate_kernel<<<BT_, 256, 0, stream>>>(x, gw, XQb, GT);
    gemm_bf16_kernel<4, true><<<dim3(E3_/128, BT_/128), 256, 0, stream>>>(XQb, WQb, scales, 0, QKVb, BT_, E3_, DIM_);
    qkv_post_kernel<<<BT_, 256, 0, stream>>>(QKVb, ve, lam, cosb, sinb, Qb, Kb, Vb);
    transpose_v_kernel<<<dim3(T_/64, HD_/64, B_*H_), 256, 0, stream>>>(Vb, VT);
    attn_kernel<<<512, 256, 0, stream>>>(Qb, Kb, VT, GT, Yb);
    gemm_bf16_kernel<4, false><<<dim3(DIM_/128, BT_/128), 256, 0, stream>>>(Yb, WQb + (size_t)3*DIM_*DIM_, scales, 3,
                                                                            (float*)d_out, BT_, DIM_, DIM_);
}

// Round 12
// 145.762 us; speedup vs baseline: 1.5782x; 1.0197x over previous
//
#include <hip/hip_runtime.h>
#include <hip/hip_bf16.h>
#include <cstddef>
#include <cstdint>

#define B_    2
#define T_    2048
#define DIM_  1024
#define H_    8
#define HD_   128
#define BT_   (B_*T_)           // 4096
#define E3_   (3*H_*HD_)        // 3072
#define F32_EPS_ 1.1920929e-07f
#define QSC_  0.17312340490667562f   // 0.12 * log2(e): softmax runs in log2 domain

typedef __attribute__((ext_vector_type(8))) short bh8_t;
typedef __attribute__((ext_vector_type(4))) float f32x4_t;
typedef __attribute__((ext_vector_type(16))) float f32x16_t;
typedef __attribute__((ext_vector_type(4))) unsigned short us4_t;

__device__ inline unsigned short bf16r(float f) {
    unsigned u = __builtin_bit_cast(unsigned, f);
    u = (u + 0x7fffu + ((u >> 16) & 1u)) >> 16;
    return (unsigned short)u;
}
__device__ inline float b2f(unsigned short u) {
    return __builtin_bit_cast(float, (unsigned)u << 16);
}
__device__ inline unsigned cvtpk(float a, float b) {
    unsigned r;
    asm("v_cvt_pk_bf16_f32 %0, %1, %2" : "=v"(r) : "v"(a), "v"(b));
    return r;
}
__device__ inline void gl16(const unsigned short* g, unsigned short* l) {
    __builtin_amdgcn_global_load_lds((const __attribute__((address_space(1))) void*)g,
                                     (__attribute__((address_space(3))) void*)l, 16, 0, 0);
}

// ---------------- K1a: per-chunk |w| partial sums ----------------
__global__ __launch_bounds__(256) void absmean1_kernel(const float* __restrict__ w, float* __restrict__ partial) {
    int blk = blockIdx.x;
    size_t off = (size_t)blk * 4096;
    __shared__ float red[256];
    int tid = threadIdx.x;
    float acc = 0.f;
    const float* p = w + off + tid*16;
    #pragma unroll
    for (int j = 0; j < 4; j++) {
        float4 v = *(const float4*)(p + j*4);
        acc += fabsf(v.x) + fabsf(v.y) + fabsf(v.z) + fabsf(v.w);
    }
    red[tid] = acc; __syncthreads();
    for (int s = 128; s > 0; s >>= 1) { if (tid < s) red[tid] += red[tid+s]; __syncthreads(); }
    if (tid == 0) partial[blk] = red[0];
}

// ---------------- K1b: finalize 4 scales ----------------
__global__ __launch_bounds__(256) void absmean2_kernel(const float* __restrict__ partial, float* __restrict__ scales) {
    int m = blockIdx.x;
    __shared__ float red[256];
    int tid = threadIdx.x;
    red[tid] = partial[m*256 + tid]; __syncthreads();
    for (int s = 128; s > 0; s >>= 1) { if (tid < s) red[tid] += red[tid+s]; __syncthreads(); }
    if (tid == 0) scales[m] = fmaxf(red[0] / (float)(DIM_*DIM_), 1e-5f);
}

// ---------------- K2: ternary-quantize weights -> bf16 {-1,0,+1} ----------------
__global__ __launch_bounds__(256) void quant_w_kernel(const float* __restrict__ w, const float* __restrict__ scales,
                                                      unsigned short* __restrict__ wq) {
    int base = (blockIdx.x * 256 + threadIdx.x) * 8;
    float s = scales[base >> 20];
    float inv = 1.f / s;
    unsigned short out[8];
    float4 v0 = *(const float4*)(w + base);
    float4 v1 = *(const float4*)(w + base + 4);
    float t[8] = {v0.x, v0.y, v0.z, v0.w, v1.x, v1.y, v1.z, v1.w};
    #pragma unroll
    for (int j = 0; j < 8; j++) {
        float r = rintf(t[j] * inv);
        r = fminf(1.f, fmaxf(-1.f, r));
        out[j] = (r == 0.f) ? 0 : (r > 0.f ? 0x3F80 : 0xBF80);
    }
    *(int4*)(wq + base) = *(const int4*)out;
}

// ---------------- K3: per-row 8-bit quant of x (bf16 out) + gate ----------------
__global__ __launch_bounds__(256) void quant_x_gate_kernel(const float* __restrict__ x, const float* __restrict__ gw,
                                                           unsigned short* __restrict__ xqb, float* __restrict__ gate) {
    int row = blockIdx.x;
    const float* xr = x + (size_t)row * DIM_;
    unsigned short* qr = xqb + (size_t)row * DIM_;
    __shared__ float red[256];
    __shared__ float x12[12];
    int tid = threadIdx.x;
    float v[4];
    float mn = 1e30f, mx = -1e30f;
    #pragma unroll
    for (int i = 0; i < 4; i++) {
        v[i] = xr[i*256 + tid];
        mn = fminf(mn, v[i]); mx = fmaxf(mx, v[i]);
    }
    red[tid] = mn; __syncthreads();
    for (int s = 128; s > 0; s >>= 1) { if (tid < s) red[tid] = fminf(red[tid], red[tid+s]); __syncthreads(); }
    mn = red[0]; __syncthreads();
    red[tid] = mx; __syncthreads();
    for (int s = 128; s > 0; s >>= 1) { if (tid < s) red[tid] = fmaxf(red[tid], red[tid+s]); __syncthreads(); }
    mx = red[0]; __syncthreads();
    float p = fmaxf(mx, 1e-5f);
    float n = fminf(mn, -1e-5f);
    #pragma unroll
    for (int i = 0; i < 4; i++) {
        int gi = i*256 + tid;
        float xv = v[i];
        float sc = (xv >= 0.f) ? p : n;
        float q = rintf(xv / sc * 127.f) / 127.f * sc;
        qr[gi] = bf16r(q);
        if (gi < 12) x12[gi] = q;
    }
    __syncthreads();
    if (tid < H_) {
        float acc = 0.f;
        #pragma unroll
        for (int f = 0; f < 12; f++) acc += x12[f] * gw[tid*12 + f];
        gate[(size_t)row * H_ + tid] = 1.f / (1.f + expf(-acc));
    }
}

// ---------------- bf16 MFMA GEMM. BM = MT*32, BN = 128, BK = 64. OBF: bf16 output ----------------
template<int MT, bool OBF>
__global__ __launch_bounds__(256) void gemm_bf16_kernel(const unsigned short* __restrict__ A,
                                                        const unsigned short* __restrict__ Bm,
                                                        const float* __restrict__ sw, int sbase,
                                                        void* __restrict__ Cv, int M, int N, int K) {
    __shared__ __align__(16) unsigned short As[MT*32*64];
    __shared__ __align__(16) unsigned short Bs[128*64];
    int bm = blockIdx.y * (MT*32), bn = blockIdx.x * 128;
    int tid = threadIdx.x;
    int w = tid >> 6, l = tid & 63;
    int wr = w >> 1, wc = w & 1;
    int lg = l >> 4, lq = l & 15;
    f32x4_t acc[MT][4];
    #pragma unroll
    for (int mt = 0; mt < MT; mt++)
        #pragma unroll
        for (int nt = 0; nt < 4; nt++) acc[mt][nt] = (f32x4_t)0.f;

    for (int k0 = 0; k0 < K; k0 += 64) {
        #pragma unroll
        for (int i = 0; i < MT; i++) {
            int ob = (i*4 + w) << 10;
            int o  = ob + (l << 4);
            int row = o >> 7;
            int lcn = ((o >> 4) & 7) ^ (row & 7);
            gl16(A + (size_t)(bm+row)*K + k0 + lcn*8, (unsigned short*)As + (ob >> 1));
        }
        #pragma unroll
        for (int i = 0; i < 4; i++) {
            int ob = (i*4 + w) << 10;
            int o  = ob + (l << 4);
            int row = o >> 7;
            int lcn = ((o >> 4) & 7) ^ (row & 7);
            gl16(Bm + (size_t)(bn+row)*K + k0 + lcn*8, (unsigned short*)Bs + (ob >> 1));
        }
        __syncthreads();
        #pragma unroll
        for (int kk = 0; kk < 2; kk++) {
            bh8_t af[MT], bf[4];
            #pragma unroll
            for (int mt = 0; mt < MT; mt++) {
                int r = wr*(MT*16) + mt*16 + lq;
                int j = kk*4 + lg;
                af[mt] = *(const bh8_t*)(As + r*64 + (((j ^ (r & 7)))<<3));
            }
            #pragma unroll
            for (int nt = 0; nt < 4; nt++) {
                int r = wc*64 + nt*16 + lq;
                int j = kk*4 + lg;
                bf[nt] = *(const bh8_t*)(Bs + r*64 + (((j ^ (r & 7)))<<3));
            }
            #pragma unroll
            for (int mt = 0; mt < MT; mt++)
                #pragma unroll
                for (int nt = 0; nt < 4; nt++)
                    acc[mt][nt] = __builtin_amdgcn_mfma_f32_16x16x32_bf16(af[mt], bf[nt], acc[mt][nt], 0, 0, 0);
        }
        __syncthreads();
    }
    #pragma unroll
    for (int nt = 0; nt < 4; nt++) {
        int col = bn + wc*64 + nt*16 + lq;
        float s = sw[sbase + (col >> 10)];
        #pragma unroll
        for (int mt = 0; mt < MT; mt++) {
            int row = bm + wr*(MT*16) + mt*16 + lg*4;
            #pragma unroll
            for (int r = 0; r < 4; r++) {
                if constexpr (OBF)
                    ((unsigned short*)Cv)[(size_t)(row + r)*N + col] = bf16r(acc[mt][nt][r] * s);
                else
                    ((float*)Cv)[(size_t)(row + r)*N + col] = acc[mt][nt][r] * s;
            }
        }
    }
}

// ---------------- K5: rmsnorm/rotary/quant for Q,K only (wave-per-row, shfl, no LDS) ----------------
__global__ __launch_bounds__(256) void qkv_post_kernel(const unsigned short* __restrict__ qkvb,
                                                       const float* __restrict__ cosb, const float* __restrict__ sinb,
                                                       unsigned short* __restrict__ Qb, unsigned short* __restrict__ Kb) {
    int bt = blockIdx.x;
    int b = bt >> 11, t = bt & (T_ - 1);
    int w = threadIdx.x >> 6, l = threadIdx.x & 63;
    const unsigned short* base = qkvb + (size_t)bt * E3_;
    float cc = cosb[(size_t)t*64 + l], ss = sinb[(size_t)t*64 + l];
    #pragma unroll
    for (int i = 0; i < 4; i++) {
        int part = w*4 + i;                 // 0..15
        const unsigned short* row = base + part*HD_;
        float x1 = b2f(row[l]), x2 = b2f(row[l+64]);
        float ssq = x1*x1 + x2*x2;
        #pragma unroll
        for (int off = 1; off < 64; off <<= 1) ssq += __shfl_xor(ssq, off);
        float rms = 1.0f / sqrtf(ssq / 128.0f + F32_EPS_);
        x1 *= rms; x2 *= rms;
        float o1 = x1*cc + x2*ss;
        float o2 = -x1*ss + x2*cc;
        float mn = fminf(o1, o2), mx = fmaxf(o1, o2);
        #pragma unroll
        for (int off = 1; off < 64; off <<= 1) {
            mn = fminf(mn, __shfl_xor(mn, off));
            mx = fmaxf(mx, __shfl_xor(mx, off));
        }
        float p = fmaxf(mx, 1e-5f);
        float n = fminf(mn, -1e-5f);
        float s1 = (o1 >= 0.f) ? p : n;
        float s2 = (o2 >= 0.f) ? p : n;
        float q1 = rintf(o1 / s1 * 127.f) / 127.f * s1;
        float q2 = rintf(o2 / s2 * 127.f) / 127.f * s2;
        if (part < 8) {
            unsigned short* dst = Qb + ((size_t)(b*H_+part)*T_ + t)*HD_;
            dst[l] = bf16r(QSC_ * q1); dst[l + 64] = bf16r(QSC_ * q2);
        } else {
            unsigned short* dst = Kb + ((size_t)(b*H_+part-8)*T_ + t)*HD_;
            dst[l] = bf16r(q1); dst[l + 64] = bf16r(q2);
        }
    }
}

// ---------------- K6: fused ve-mix + transpose V: VT[bh][d][t] = bf16(l0*QKVb_v + l1*ve) ----------------
__global__ __launch_bounds__(256) void transpose_v_kernel(const unsigned short* __restrict__ qkvb,
                                                          const float* __restrict__ ve,
                                                          const float* __restrict__ lam,
                                                          unsigned short* __restrict__ VT) {
    int tt = blockIdx.x;
    int dt = blockIdx.y;
    int bh = blockIdx.z;
    int b = bh >> 3, h = bh & 7;
    __shared__ unsigned short L[64][80];
    int tid = threadIdx.x;
    float l0 = lam[0], l1 = lam[1];
    #pragma unroll
    for (int i = 0; i < 2; i++) {
        int c = tid + i*256;
        int r = c >> 3, dc = c & 7;
        size_t bt = (size_t)(b*T_ + tt*64 + r);
        union { int4 v; unsigned short q[8]; } u;
        u.v = *(const int4*)(qkvb + bt*E3_ + (16 + h)*HD_ + dt*64 + dc*8);
        float4 va = *(const float4*)(ve + bt*DIM_ + h*HD_ + dt*64 + dc*8);
        float4 vb = *(const float4*)(ve + bt*DIM_ + h*HD_ + dt*64 + dc*8 + 4);
        float vv[8] = {va.x, va.y, va.z, va.w, vb.x, vb.y, vb.z, vb.w};
        unsigned short mix[8];
        #pragma unroll
        for (int k = 0; k < 8; k++) mix[k] = bf16r(l0*b2f(u.q[k]) + l1*vv[k]);
        *(int4*)(&L[r][dc*8]) = *(const int4*)mix;
    }
    __syncthreads();
    #pragma unroll
    for (int i = 0; i < 2; i++) {
        int c = tid + i*256;
        int r = c >> 3, tc = c & 7;
        unsigned short tmp[8];
        #pragma unroll
        for (int jj = 0; jj < 8; jj++) tmp[jj] = L[tc*8+jj][r];
        *(int4*)(VT + ((size_t)bh*HD_ + dt*64 + r)*T_ + tt*64 + tc*8) = *(const int4*)tmp;
    }
}

// ---------------- K7: flash attention (r6 structure, best measured) ----------------
__global__ __launch_bounds__(256) void attn_kernel(const unsigned short* __restrict__ Qb,
                                                   const unsigned short* __restrict__ Kb,
                                                   const unsigned short* __restrict__ VT,
                                                   const float* __restrict__ gate,
                                                   unsigned short* __restrict__ Yb) {
    __shared__ __align__(16) unsigned char SMEM[65536];   // K[2]:2x16KB | V[2]:2x16KB
    int id = blockIdx.x;
    int bh = id & 15;
    int qi = id >> 4;
    int qt = (qi < 16) ? (31 - qi) : (qi - 16);           // pair big with small per CU
    int b = bh >> 3, h = bh & 7;
    int tid = threadIdx.x;
    int w = tid >> 6, l = tid & 63;
    int qsub = w >> 1, qq = w & 1;
    int hh = l >> 5, l5 = l & 31;
    int qrow = qsub*32 + l5;
    int qg = qt*64 + qrow;

    const unsigned short* Kbase = Kb + (size_t)bh*T_*HD_;
    const unsigned short* Vbase = VT + (size_t)bh*HD_*T_;
    const unsigned short* Qg = Qb + ((size_t)bh*T_ + (size_t)qt*64) * HD_;

    bh8_t qf[8];
    #pragma unroll
    for (int ks = 0; ks < 8; ks++)
        qf[ks] = *(const bh8_t*)(Qg + (size_t)qrow*HD_ + ks*16 + hh*8);

    int nr = qt + 1;

    f32x16_t o0 = (f32x16_t)0.f, o1 = (f32x16_t)0.f, o2 = (f32x16_t)0.f, o3 = (f32x16_t)0.f;
    float mrun = -1e20f, lrun = 0.f;

    // K: 4-bit XOR swizzle (16-chunk rows, 2-way = free); V: 3-bit (8-chunk rows)
#define STAGE(BI, J) { \
    unsigned short* kb_ = (unsigned short*)(SMEM + (BI)*16384); \
    unsigned short* vb_ = (unsigned short*)(SMEM + 32768 + (BI)*16384); \
    _Pragma("unroll") \
    for (int i_ = 0; i_ < 4; i_++) { \
        int ob_ = (i_*4 + w) << 10; \
        int o_  = ob_ + (l << 4); \
        int rk_ = o_ >> 8; \
        int lk_ = ((o_ >> 4) & 15) ^ (rk_ & 15); \
        gl16(Kbase + (size_t)((J)*64 + rk_)*HD_ + lk_*8, kb_ + (ob_ >> 1)); \
        int rv_ = o_ >> 7; \
        int lv_ = ((o_ >> 4) & 7) ^ (rv_ & 7); \
        gl16(Vbase + (size_t)rv_*T_ + (J)*64 + lv_*8, vb_ + (ob_ >> 1)); \
    } }

    STAGE(0, 0);
    for (int j = 0; j < nr; j++) {
        if (j + 1 < nr) {
            STAGE((j+1) & 1, j+1);
            asm volatile("s_waitcnt vmcnt(8)" ::: "memory");
        } else {
            asm volatile("s_waitcnt vmcnt(0)" ::: "memory");
        }
        __builtin_amdgcn_s_barrier();
        asm volatile("" ::: "memory");
        const unsigned short* kb = (const unsigned short*)(SMEM + (j&1)*16384);
        const unsigned short* vb = (const unsigned short*)(SMEM + 32768 + (j&1)*16384);
        int kvb = j*64 + qq*32;
        if (kvb <= qt*64 + qsub*32 + 31) {
            // S^T(32k x 32q) = K_half @ Q^T   (log2 domain: Q pre-scaled by 0.12*log2e)
            f32x16_t s = (f32x16_t)0.f;
            int krow = qq*32 + l5;
            __builtin_amdgcn_s_setprio(1);
            #pragma unroll
            for (int ks = 0; ks < 8; ks++) {
                int c = (ks*2 + hh) ^ (krow & 15);
                bh8_t kf = *(const bh8_t*)(kb + krow*128 + c*8);
                s = __builtin_amdgcn_mfma_f32_32x32x16_bf16(kf, qf[ks], s, 0, 0, 0);
            }
            __builtin_amdgcn_s_setprio(0);
            if (kvb + 31 > qt*64 + qsub*32) {
                #pragma unroll
                for (int r = 0; r < 16; r++) {
                    int key = kvb + (r & 3) + 8*(r >> 2) + 4*hh;
                    if (key > qg) s[r] = -1e30f;
                }
            }
            // online softmax, defer-max THR=8 (P bounded by 2^8)
            float t8[8], t4[4];
            #pragma unroll
            for (int r = 0; r < 8; r++) t8[r] = fmaxf(s[2*r], s[2*r+1]);
            #pragma unroll
            for (int r = 0; r < 4; r++) t4[r] = fmaxf(t8[2*r], t8[2*r+1]);
            float tm = fmaxf(fmaxf(t4[0], t4[1]), fmaxf(t4[2], t4[3]));
            tm = fmaxf(tm, __shfl_xor(tm, 32));
            if (!__all(tm - mrun <= 8.f)) {
                float mnew = fmaxf(mrun, tm);
                float scf = __builtin_amdgcn_exp2f(mrun - mnew);
                lrun *= scf;
                o0 *= scf; o1 *= scf; o2 *= scf; o3 *= scf;
                mrun = mnew;
            }
            float p[16];
            #pragma unroll
            for (int r = 0; r < 16; r++) p[r] = __builtin_amdgcn_exp2f(s[r] - mrun);
            #pragma unroll
            for (int r = 0; r < 8; r++) t8[r] = p[2*r] + p[2*r+1];
            #pragma unroll
            for (int r = 0; r < 4; r++) t4[r] = t8[2*r] + t8[2*r+1];
            float ls = (t4[0] + t4[1]) + (t4[2] + t4[3]);
            ls += __shfl_xor(ls, 32);
            lrun += ls;
            // pack P -> bf16 B-frags (v_cvt_pk) via lane<->lane+32 exchange
            unsigned u0 = cvtpk(p[0], p[1]),   u1 = cvtpk(p[2], p[3]);
            unsigned u2 = cvtpk(p[4], p[5]),   u3 = cvtpk(p[6], p[7]);
            unsigned u4 = cvtpk(p[8], p[9]),   u5 = cvtpk(p[10], p[11]);
            unsigned u6 = cvtpk(p[12], p[13]), u7 = cvtpk(p[14], p[15]);
            unsigned x0 = (unsigned)__shfl_xor((int)u0, 32), x1 = (unsigned)__shfl_xor((int)u1, 32);
            unsigned x2 = (unsigned)__shfl_xor((int)u2, 32), x3 = (unsigned)__shfl_xor((int)u3, 32);
            unsigned x4 = (unsigned)__shfl_xor((int)u4, 32), x5 = (unsigned)__shfl_xor((int)u5, 32);
            unsigned x6 = (unsigned)__shfl_xor((int)u6, 32), x7 = (unsigned)__shfl_xor((int)u7, 32);
            union { bh8_t v; unsigned uu[4]; } B0, B1;
            B0.uu[0] = hh ? x2 : u0;  B0.uu[1] = hh ? x3 : u1;
            B0.uu[2] = hh ? u2 : x0;  B0.uu[3] = hh ? u3 : x1;
            B1.uu[0] = hh ? x6 : u4;  B1.uu[1] = hh ? x7 : u5;
            B1.uu[2] = hh ? u6 : x4;  B1.uu[3] = hh ? u7 : x5;
            // O^T(128d x 32q) += V^T_half @ P^T
            __builtin_amdgcn_s_setprio(1);
#define PV_STEP(DT, OACC) { \
    int vrow = DT*32 + l5; \
    bh8_t vf0 = *(const bh8_t*)(vb + vrow*64 + (((qq*4 + hh) ^ (vrow & 7))<<3)); \
    OACC = __builtin_amdgcn_mfma_f32_32x32x16_bf16(vf0, B0.v, OACC, 0, 0, 0); \
    bh8_t vf1 = *(const bh8_t*)(vb + vrow*64 + (((qq*4 + 2 + hh) ^ (vrow & 7))<<3)); \
    OACC = __builtin_amdgcn_mfma_f32_32x32x16_bf16(vf1, B1.v, OACC, 0, 0, 0); }
            PV_STEP(0, o0) PV_STEP(1, o1) PV_STEP(2, o2) PV_STEP(3, o3)
#undef PV_STEP
            __builtin_amdgcn_s_setprio(0);
        }
        asm volatile("s_waitcnt lgkmcnt(0)" ::: "memory");
        __builtin_amdgcn_s_barrier();
        asm volatile("" ::: "memory");
    }

    // ---- 2-way stream merge per qsub (LDS reuse), then epilogue ----
    f32x16_t oA[4] = {o0, o1, o2, o3};
    float* OB = (float*)SMEM;
    float* ML = (float*)(SMEM + 32768);
    unsigned short* YS = (unsigned short*)(SMEM + 33280);
    if (qq != 0) {
        float* obuf = OB + (size_t)qsub * 4096;
        #pragma unroll
        for (int dt = 0; dt < 4; dt++)
            #pragma unroll
            for (int g = 0; g < 4; g++) {
                f32x4_t v4;
                #pragma unroll
                for (int e = 0; e < 4; e++) v4[e] = oA[dt][g*4+e];
                int ch = (dt*4 + g) ^ (l & 7);
                *(f32x4_t*)(obuf + l*64 + ch*4) = v4;
            }
        if (hh == 0) {
            ML[(qsub*32 + l5)*2]     = mrun;
            ML[(qsub*32 + l5)*2 + 1] = lrun;
        }
    }
    __syncthreads();
    if (qq == 0) {
        float mb = ML[(qsub*32 + l5)*2];
        float lb = ML[(qsub*32 + l5)*2 + 1];
        float mN = fmaxf(mrun, mb);
        float fa = __builtin_amdgcn_exp2f(mrun - mN), fb = __builtin_amdgcn_exp2f(mb - mN);
        const float* obuf = OB + (size_t)qsub * 4096;
        #pragma unroll
        for (int dt = 0; dt < 4; dt++)
            #pragma unroll
            for (int g = 0; g < 4; g++) {
                int ch = (dt*4 + g) ^ (l & 7);
                f32x4_t v4 = *(const f32x4_t*)(obuf + l*64 + ch*4);
                #pragma unroll
                for (int e = 0; e < 4; e++)
                    oA[dt][g*4+e] = oA[dt][g*4+e]*fa + v4[e]*fb;
            }
        lrun = lrun*fa + lb*fb;
        float gv = gate[((size_t)b*T_ + (size_t)qg)*H_ + h];
        float inv = gv / lrun;
        #pragma unroll
        for (int dt = 0; dt < 4; dt++)
            #pragma unroll
            for (int g = 0; g < 4; g++) {
                unsigned short pk4[4];
                #pragma unroll
                for (int e = 0; e < 4; e++) pk4[e] = bf16r(oA[dt][g*4+e] * inv);
                int ch = (dt*4 + g) ^ (qrow & 7);
                *(us4_t*)(YS + (size_t)qrow*128 + ch*8 + hh*4) = *(const us4_t*)pk4;
            }
    }
    __syncthreads();
    #pragma unroll
    for (int i = 0; i < 4; i++) {
        int idx = tid + i*256;
        int r = idx >> 4, scn = idx & 15;
        int lcn = scn ^ (r & 7);
        int4 v = *(const int4*)(YS + (size_t)r*128 + scn*8);
        *(int4*)(Yb + (size_t)(b*T_ + qt*64 + r)*DIM_ + h*HD_ + lcn*8) = v;
    }
#undef STAGE
}

extern "C" void kernel_launch(void* const* d_in, const int* in_sizes, int n_in,
                              void* d_out, int out_size, void* d_ws, size_t ws_size,
                              hipStream_t stream) {
    const float* x    = (const float*)d_in[0];
    const float* ve   = (const float*)d_in[1];
    const float* lam  = (const float*)d_in[2];
    const float* cosb = (const float*)d_in[3];
    const float* sinb = (const float*)d_in[4];
    const float* qkvo = (const float*)d_in[5];
    const float* gw   = (const float*)d_in[6];

    char* ws = (char*)d_ws;
    float* scales  = (float*)ws;
    float* partial = scales + 16;
    unsigned short* WQb  = (unsigned short*)(ws + (1<<13));           // 8 MB
    unsigned short* XQb  = WQb + (size_t)4*DIM_*DIM_;                 // 8 MB
    unsigned short* QKVb = XQb + (size_t)BT_*DIM_;                    // 24 MB (later: Yb)
    float* GT = (float*)(QKVb + (size_t)BT_*E3_);                     // 128 KB
    unsigned short* Qb = (unsigned short*)(GT + (size_t)BT_*H_);      // 8 MB
    unsigned short* Kb = Qb + (size_t)B_*H_*T_*HD_;                   // 8 MB
    unsigned short* VT = Kb + (size_t)B_*H_*T_*HD_;                   // 8 MB
    unsigned short* Yb = QKVb;                                        // reuse (dead after qkv_post+transpose)

    absmean1_kernel<<<1024, 256, 0, stream>>>(qkvo, partial);
    absmean2_kernel<<<4, 256, 0, stream>>>(partial, scales);
    quant_w_kernel<<<(4*DIM_*DIM_)/(256*8), 256, 0, stream>>>(qkvo, scales, WQb);
    quant_x_gate_kernel<<<BT_, 256, 0, stream>>>(x, gw, XQb, GT);
    gemm_bf16_kernel<4, true><<<dim3(E3_/128, BT_/128), 256, 0, stream>>>(XQb, WQb, scales, 0, QKVb, BT_, E3_, DIM_);
    qkv_post_kernel<<<BT_, 256, 0, stream>>>(QKVb, cosb, sinb, Qb, Kb);
    transpose_v_kernel<<<dim3(T_/64, HD_/64, B_*H_), 256, 0, stream>>>(QKVb, ve, lam, VT);
    attn_kernel<<<512, 256, 0, stream>>>(Qb, Kb, VT, GT, Yb);
    gemm_bf16_kernel<2, false><<<dim3(DIM_/128, BT_/64), 256, 0, stream>>>(Yb, WQb + (size_t)3*DIM_*DIM_, scales, 3,
                                                                           (float*)d_out, BT_, DIM_, DIM_);
}

// Round 13
// 141.069 us; speedup vs baseline: 1.6307x; 1.0333x over previous
//
#include <hip/hip_runtime.h>
#include <hip/hip_bf16.h>
#include <cstddef>
#include <cstdint>

#define B_    2
#define T_    2048
#define DIM_  1024
#define H_    8
#define HD_   128
#define BT_   (B_*T_)           // 4096
#define E3_   (3*H_*HD_)        // 3072
#define F32_EPS_ 1.1920929e-07f
#define QSC_  0.17312340490667562f   // 0.12 * log2(e): softmax runs in log2 domain

typedef __attribute__((ext_vector_type(8))) short bh8_t;
typedef __attribute__((ext_vector_type(4))) float f32x4_t;
typedef __attribute__((ext_vector_type(16))) float f32x16_t;
typedef __attribute__((ext_vector_type(4))) unsigned short us4_t;

__device__ inline unsigned short bf16r(float f) {
    unsigned u = __builtin_bit_cast(unsigned, f);
    u = (u + 0x7fffu + ((u >> 16) & 1u)) >> 16;
    return (unsigned short)u;
}
__device__ inline float b2f(unsigned short u) {
    return __builtin_bit_cast(float, (unsigned)u << 16);
}
__device__ inline unsigned cvtpk(float a, float b) {
    unsigned r;
    asm("v_cvt_pk_bf16_f32 %0, %1, %2" : "=v"(r) : "v"(a), "v"(b));
    return r;
}
__device__ inline void gl16(const unsigned short* g, unsigned short* l) {
    __builtin_amdgcn_global_load_lds((const __attribute__((address_space(1))) void*)g,
                                     (__attribute__((address_space(3))) void*)l, 16, 0, 0);
}

// ---------------- K1a: per-chunk |w| partial sums ----------------
__global__ __launch_bounds__(256) void absmean1_kernel(const float* __restrict__ w, float* __restrict__ partial) {
    int blk = blockIdx.x;
    size_t off = (size_t)blk * 4096;
    __shared__ float red[256];
    int tid = threadIdx.x;
    float acc = 0.f;
    const float* p = w + off + tid*16;
    #pragma unroll
    for (int j = 0; j < 4; j++) {
        float4 v = *(const float4*)(p + j*4);
        acc += fabsf(v.x) + fabsf(v.y) + fabsf(v.z) + fabsf(v.w);
    }
    red[tid] = acc; __syncthreads();
    for (int s = 128; s > 0; s >>= 1) { if (tid < s) red[tid] += red[tid+s]; __syncthreads(); }
    if (tid == 0) partial[blk] = red[0];
}

// ---------------- K1b: finalize 4 scales ----------------
__global__ __launch_bounds__(256) void absmean2_kernel(const float* __restrict__ partial, float* __restrict__ scales) {
    int m = blockIdx.x;
    __shared__ float red[256];
    int tid = threadIdx.x;
    red[tid] = partial[m*256 + tid]; __syncthreads();
    for (int s = 128; s > 0; s >>= 1) { if (tid < s) red[tid] += red[tid+s]; __syncthreads(); }
    if (tid == 0) scales[m] = fmaxf(red[0] / (float)(DIM_*DIM_), 1e-5f);
}

// ---------------- K2: ternary-quantize weights -> bf16 {-1,0,+1} ----------------
__global__ __launch_bounds__(256) void quant_w_kernel(const float* __restrict__ w, const float* __restrict__ scales,
                                                      unsigned short* __restrict__ wq) {
    int base = (blockIdx.x * 256 + threadIdx.x) * 8;
    float s = scales[base >> 20];
    float inv = 1.f / s;
    unsigned short out[8];
    float4 v0 = *(const float4*)(w + base);
    float4 v1 = *(const float4*)(w + base + 4);
    float t[8] = {v0.x, v0.y, v0.z, v0.w, v1.x, v1.y, v1.z, v1.w};
    #pragma unroll
    for (int j = 0; j < 8; j++) {
        float r = rintf(t[j] * inv);
        r = fminf(1.f, fmaxf(-1.f, r));
        out[j] = (r == 0.f) ? 0 : (r > 0.f ? 0x3F80 : 0xBF80);
    }
    *(int4*)(wq + base) = *(const int4*)out;
}

// ---------------- K3: per-row 8-bit quant of x (bf16 out) + gate; shfl reductions ----------------
__global__ __launch_bounds__(256) void quant_x_gate_kernel(const float* __restrict__ x, const float* __restrict__ gw,
                                                           unsigned short* __restrict__ xqb, float* __restrict__ gate) {
    int row = blockIdx.x;
    const float* xr = x + (size_t)row * DIM_;
    unsigned short* qr = xqb + (size_t)row * DIM_;
    __shared__ float wmn[4], wmx[4];
    __shared__ float x12[12];
    int tid = threadIdx.x;
    int w = tid >> 6, l = tid & 63;
    float v[4];
    float mn = 1e30f, mx = -1e30f;
    #pragma unroll
    for (int i = 0; i < 4; i++) {
        v[i] = xr[i*256 + tid];
        mn = fminf(mn, v[i]); mx = fmaxf(mx, v[i]);
    }
    #pragma unroll
    for (int off = 1; off < 64; off <<= 1) {
        mn = fminf(mn, __shfl_xor(mn, off));
        mx = fmaxf(mx, __shfl_xor(mx, off));
    }
    if (l == 0) { wmn[w] = mn; wmx[w] = mx; }
    __syncthreads();
    mn = fminf(fminf(wmn[0], wmn[1]), fminf(wmn[2], wmn[3]));
    mx = fmaxf(fmaxf(wmx[0], wmx[1]), fmaxf(wmx[2], wmx[3]));
    float p = fmaxf(mx, 1e-5f);
    float n = fminf(mn, -1e-5f);
    #pragma unroll
    for (int i = 0; i < 4; i++) {
        int gi = i*256 + tid;
        float xv = v[i];
        float sc = (xv >= 0.f) ? p : n;
        float q = rintf(xv / sc * 127.f) / 127.f * sc;
        qr[gi] = bf16r(q);
        if (gi < 12) x12[gi] = q;
    }
    __syncthreads();
    if (tid < H_) {
        float acc = 0.f;
        #pragma unroll
        for (int f = 0; f < 12; f++) acc += x12[f] * gw[tid*12 + f];
        gate[(size_t)row * H_ + tid] = 1.f / (1.f + expf(-acc));
    }
}

// ---------------- bf16 MFMA GEMM. BM = MT*32, BN = 128, BK = 64. OBF: bf16 output ----------------
template<int MT, bool OBF>
__global__ __launch_bounds__(256) void gemm_bf16_kernel(const unsigned short* __restrict__ A,
                                                        const unsigned short* __restrict__ Bm,
                                                        const float* __restrict__ sw, int sbase,
                                                        void* __restrict__ Cv, int M, int N, int K) {
    __shared__ __align__(16) unsigned short As[MT*32*64];
    __shared__ __align__(16) unsigned short Bs[128*64];
    int bm = blockIdx.y * (MT*32), bn = blockIdx.x * 128;
    int tid = threadIdx.x;
    int w = tid >> 6, l = tid & 63;
    int wr = w >> 1, wc = w & 1;
    int lg = l >> 4, lq = l & 15;
    f32x4_t acc[MT][4];
    #pragma unroll
    for (int mt = 0; mt < MT; mt++)
        #pragma unroll
        for (int nt = 0; nt < 4; nt++) acc[mt][nt] = (f32x4_t)0.f;

    for (int k0 = 0; k0 < K; k0 += 64) {
        #pragma unroll
        for (int i = 0; i < MT; i++) {
            int ob = (i*4 + w) << 10;
            int o  = ob + (l << 4);
            int row = o >> 7;
            int lcn = ((o >> 4) & 7) ^ (row & 7);
            gl16(A + (size_t)(bm+row)*K + k0 + lcn*8, (unsigned short*)As + (ob >> 1));
        }
        #pragma unroll
        for (int i = 0; i < 4; i++) {
            int ob = (i*4 + w) << 10;
            int o  = ob + (l << 4);
            int row = o >> 7;
            int lcn = ((o >> 4) & 7) ^ (row & 7);
            gl16(Bm + (size_t)(bn+row)*K + k0 + lcn*8, (unsigned short*)Bs + (ob >> 1));
        }
        __syncthreads();
        #pragma unroll
        for (int kk = 0; kk < 2; kk++) {
            bh8_t af[MT], bf[4];
            #pragma unroll
            for (int mt = 0; mt < MT; mt++) {
                int r = wr*(MT*16) + mt*16 + lq;
                int j = kk*4 + lg;
                af[mt] = *(const bh8_t*)(As + r*64 + (((j ^ (r & 7)))<<3));
            }
            #pragma unroll
            for (int nt = 0; nt < 4; nt++) {
                int r = wc*64 + nt*16 + lq;
                int j = kk*4 + lg;
                bf[nt] = *(const bh8_t*)(Bs + r*64 + (((j ^ (r & 7)))<<3));
            }
            #pragma unroll
            for (int mt = 0; mt < MT; mt++)
                #pragma unroll
                for (int nt = 0; nt < 4; nt++)
                    acc[mt][nt] = __builtin_amdgcn_mfma_f32_16x16x32_bf16(af[mt], bf[nt], acc[mt][nt], 0, 0, 0);
        }
        __syncthreads();
    }
    #pragma unroll
    for (int nt = 0; nt < 4; nt++) {
        int col = bn + wc*64 + nt*16 + lq;
        float s = sw[sbase + (col >> 10)];
        #pragma unroll
        for (int mt = 0; mt < MT; mt++) {
            int row = bm + wr*(MT*16) + mt*16 + lg*4;
            #pragma unroll
            for (int r = 0; r < 4; r++) {
                if constexpr (OBF)
                    ((unsigned short*)Cv)[(size_t)(row + r)*N + col] = bf16r(acc[mt][nt][r] * s);
                else
                    ((float*)Cv)[(size_t)(row + r)*N + col] = acc[mt][nt][r] * s;
            }
        }
    }
}

// ---------------- K5: merged qkv_post (blocks 0..4095) + ve-mix/transpose-V (blocks 4096..5119) ----------------
__global__ __launch_bounds__(256) void qkv_post_tv_kernel(const unsigned short* __restrict__ qkvb,
                                                          const float* __restrict__ ve,
                                                          const float* __restrict__ lam,
                                                          const float* __restrict__ cosb, const float* __restrict__ sinb,
                                                          unsigned short* __restrict__ Qb, unsigned short* __restrict__ Kb,
                                                          unsigned short* __restrict__ VT) {
    __shared__ unsigned short L[64][80];
    int bid = blockIdx.x;
    int tid = threadIdx.x;
    if (bid < BT_) {
        // ---- rmsnorm -> rotary -> quant for Q,K (wave-per-row, shfl, no LDS) ----
        int bt = bid;
        int b = bt >> 11, t = bt & (T_ - 1);
        int w = tid >> 6, l = tid & 63;
        const unsigned short* base = qkvb + (size_t)bt * E3_;
        float cc = cosb[(size_t)t*64 + l], ss = sinb[(size_t)t*64 + l];
        #pragma unroll
        for (int i = 0; i < 4; i++) {
            int part = w*4 + i;                 // 0..15
            const unsigned short* row = base + part*HD_;
            float x1 = b2f(row[l]), x2 = b2f(row[l+64]);
            float ssq = x1*x1 + x2*x2;
            #pragma unroll
            for (int off = 1; off < 64; off <<= 1) ssq += __shfl_xor(ssq, off);
            float rms = 1.0f / sqrtf(ssq / 128.0f + F32_EPS_);
            x1 *= rms; x2 *= rms;
            float o1 = x1*cc + x2*ss;
            float o2 = -x1*ss + x2*cc;
            float mn = fminf(o1, o2), mx = fmaxf(o1, o2);
            #pragma unroll
            for (int off = 1; off < 64; off <<= 1) {
                mn = fminf(mn, __shfl_xor(mn, off));
                mx = fmaxf(mx, __shfl_xor(mx, off));
            }
            float p = fmaxf(mx, 1e-5f);
            float n = fminf(mn, -1e-5f);
            float s1 = (o1 >= 0.f) ? p : n;
            float s2 = (o2 >= 0.f) ? p : n;
            float q1 = rintf(o1 / s1 * 127.f) / 127.f * s1;
            float q2 = rintf(o2 / s2 * 127.f) / 127.f * s2;
            if (part < 8) {
                unsigned short* dst = Qb + ((size_t)(b*H_+part)*T_ + t)*HD_;
                dst[l] = bf16r(QSC_ * q1); dst[l + 64] = bf16r(QSC_ * q2);
            } else {
                unsigned short* dst = Kb + ((size_t)(b*H_+part-8)*T_ + t)*HD_;
                dst[l] = bf16r(q1); dst[l + 64] = bf16r(q2);
            }
        }
    } else {
        // ---- fused ve-mix + transpose V: VT[bh][d][t] = bf16(l0*v + l1*ve) ----
        int r0 = bid - BT_;                    // 0..1023
        int tt = r0 & 31;
        int dt = (r0 >> 5) & 1;
        int bh = r0 >> 6;
        int b = bh >> 3, h = bh & 7;
        float l0 = lam[0], l1 = lam[1];
        #pragma unroll
        for (int i = 0; i < 2; i++) {
            int c = tid + i*256;
            int r = c >> 3, dc = c & 7;
            size_t bt = (size_t)(b*T_ + tt*64 + r);
            union { int4 v; unsigned short q[8]; } u;
            u.v = *(const int4*)(qkvb + bt*E3_ + (16 + h)*HD_ + dt*64 + dc*8);
            float4 va = *(const float4*)(ve + bt*DIM_ + h*HD_ + dt*64 + dc*8);
            float4 vb = *(const float4*)(ve + bt*DIM_ + h*HD_ + dt*64 + dc*8 + 4);
            float vv[8] = {va.x, va.y, va.z, va.w, vb.x, vb.y, vb.z, vb.w};
            unsigned short mix[8];
            #pragma unroll
            for (int k = 0; k < 8; k++) mix[k] = bf16r(l0*b2f(u.q[k]) + l1*vv[k]);
            *(int4*)(&L[r][dc*8]) = *(const int4*)mix;
        }
        __syncthreads();
        #pragma unroll
        for (int i = 0; i < 2; i++) {
            int c = tid + i*256;
            int r = c >> 3, tc = c & 7;
            unsigned short tmp[8];
            #pragma unroll
            for (int jj = 0; jj < 8; jj++) tmp[jj] = L[tc*8+jj][r];
            *(int4*)(VT + ((size_t)bh*HD_ + dt*64 + r)*T_ + tt*64 + tc*8) = *(const int4*)tmp;
        }
    }
}

// ---------------- K7: flash attention (r6 structure, best measured) ----------------
__global__ __launch_bounds__(256) void attn_kernel(const unsigned short* __restrict__ Qb,
                                                   const unsigned short* __restrict__ Kb,
                                                   const unsigned short* __restrict__ VT,
                                                   const float* __restrict__ gate,
                                                   unsigned short* __restrict__ Yb) {
    __shared__ __align__(16) unsigned char SMEM[65536];   // K[2]:2x16KB | V[2]:2x16KB
    int id = blockIdx.x;
    int bh = id & 15;
    int qi = id >> 4;
    int qt = (qi < 16) ? (31 - qi) : (qi - 16);           // pair big with small per CU
    int b = bh >> 3, h = bh & 7;
    int tid = threadIdx.x;
    int w = tid >> 6, l = tid & 63;
    int qsub = w >> 1, qq = w & 1;
    int hh = l >> 5, l5 = l & 31;
    int qrow = qsub*32 + l5;
    int qg = qt*64 + qrow;

    const unsigned short* Kbase = Kb + (size_t)bh*T_*HD_;
    const unsigned short* Vbase = VT + (size_t)bh*HD_*T_;
    const unsigned short* Qg = Qb + ((size_t)bh*T_ + (size_t)qt*64) * HD_;

    bh8_t qf[8];
    #pragma unroll
    for (int ks = 0; ks < 8; ks++)
        qf[ks] = *(const bh8_t*)(Qg + (size_t)qrow*HD_ + ks*16 + hh*8);

    int nr = qt + 1;

    f32x16_t o0 = (f32x16_t)0.f, o1 = (f32x16_t)0.f, o2 = (f32x16_t)0.f, o3 = (f32x16_t)0.f;
    float mrun = -1e20f, lrun = 0.f;

    // K: 4-bit XOR swizzle (16-chunk rows, 2-way = free); V: 3-bit (8-chunk rows)
#define STAGE(BI, J) { \
    unsigned short* kb_ = (unsigned short*)(SMEM + (BI)*16384); \
    unsigned short* vb_ = (unsigned short*)(SMEM + 32768 + (BI)*16384); \
    _Pragma("unroll") \
    for (int i_ = 0; i_ < 4; i_++) { \
        int ob_ = (i_*4 + w) << 10; \
        int o_  = ob_ + (l << 4); \
        int rk_ = o_ >> 8; \
        int lk_ = ((o_ >> 4) & 15) ^ (rk_ & 15); \
        gl16(Kbase + (size_t)((J)*64 + rk_)*HD_ + lk_*8, kb_ + (ob_ >> 1)); \
        int rv_ = o_ >> 7; \
        int lv_ = ((o_ >> 4) & 7) ^ (rv_ & 7); \
        gl16(Vbase + (size_t)rv_*T_ + (J)*64 + lv_*8, vb_ + (ob_ >> 1)); \
    } }

    STAGE(0, 0);
    for (int j = 0; j < nr; j++) {
        if (j + 1 < nr) {
            STAGE((j+1) & 1, j+1);
            asm volatile("s_waitcnt vmcnt(8)" ::: "memory");
        } else {
            asm volatile("s_waitcnt vmcnt(0)" ::: "memory");
        }
        __builtin_amdgcn_s_barrier();
        asm volatile("" ::: "memory");
        const unsigned short* kb = (const unsigned short*)(SMEM + (j&1)*16384);
        const unsigned short* vb = (const unsigned short*)(SMEM + 32768 + (j&1)*16384);
        int kvb = j*64 + qq*32;
        if (kvb <= qt*64 + qsub*32 + 31) {
            // S^T(32k x 32q) = K_half @ Q^T   (log2 domain: Q pre-scaled by 0.12*log2e)
            f32x16_t s = (f32x16_t)0.f;
            int krow = qq*32 + l5;
            __builtin_amdgcn_s_setprio(1);
            #pragma unroll
            for (int ks = 0; ks < 8; ks++) {
                int c = (ks*2 + hh) ^ (krow & 15);
                bh8_t kf = *(const bh8_t*)(kb + krow*128 + c*8);
                s = __builtin_amdgcn_mfma_f32_32x32x16_bf16(kf, qf[ks], s, 0, 0, 0);
            }
            __builtin_amdgcn_s_setprio(0);
            if (kvb + 31 > qt*64 + qsub*32) {
                #pragma unroll
                for (int r = 0; r < 16; r++) {
                    int key = kvb + (r & 3) + 8*(r >> 2) + 4*hh;
                    if (key > qg) s[r] = -1e30f;
                }
            }
            // online softmax, defer-max THR=8 (P bounded by 2^8)
            float t8[8], t4[4];
            #pragma unroll
            for (int r = 0; r < 8; r++) t8[r] = fmaxf(s[2*r], s[2*r+1]);
            #pragma unroll
            for (int r = 0; r < 4; r++) t4[r] = fmaxf(t8[2*r], t8[2*r+1]);
            float tm = fmaxf(fmaxf(t4[0], t4[1]), fmaxf(t4[2], t4[3]));
            tm = fmaxf(tm, __shfl_xor(tm, 32));
            if (!__all(tm - mrun <= 8.f)) {
                float mnew = fmaxf(mrun, tm);
                float scf = __builtin_amdgcn_exp2f(mrun - mnew);
                lrun *= scf;
                o0 *= scf; o1 *= scf; o2 *= scf; o3 *= scf;
                mrun = mnew;
            }
            float p[16];
            #pragma unroll
            for (int r = 0; r < 16; r++) p[r] = __builtin_amdgcn_exp2f(s[r] - mrun);
            #pragma unroll
            for (int r = 0; r < 8; r++) t8[r] = p[2*r] + p[2*r+1];
            #pragma unroll
            for (int r = 0; r < 4; r++) t4[r] = t8[2*r] + t8[2*r+1];
            float ls = (t4[0] + t4[1]) + (t4[2] + t4[3]);
            ls += __shfl_xor(ls, 32);
            lrun += ls;
            // pack P -> bf16 B-frags (v_cvt_pk) via lane<->lane+32 exchange
            unsigned u0 = cvtpk(p[0], p[1]),   u1 = cvtpk(p[2], p[3]);
            unsigned u2 = cvtpk(p[4], p[5]),   u3 = cvtpk(p[6], p[7]);
            unsigned u4 = cvtpk(p[8], p[9]),   u5 = cvtpk(p[10], p[11]);
            unsigned u6 = cvtpk(p[12], p[13]), u7 = cvtpk(p[14], p[15]);
            unsigned x0 = (unsigned)__shfl_xor((int)u0, 32), x1 = (unsigned)__shfl_xor((int)u1, 32);
            unsigned x2 = (unsigned)__shfl_xor((int)u2, 32), x3 = (unsigned)__shfl_xor((int)u3, 32);
            unsigned x4 = (unsigned)__shfl_xor((int)u4, 32), x5 = (unsigned)__shfl_xor((int)u5, 32);
            unsigned x6 = (unsigned)__shfl_xor((int)u6, 32), x7 = (unsigned)__shfl_xor((int)u7, 32);
            union { bh8_t v; unsigned uu[4]; } B0, B1;
            B0.uu[0] = hh ? x2 : u0;  B0.uu[1] = hh ? x3 : u1;
            B0.uu[2] = hh ? u2 : x0;  B0.uu[3] = hh ? u3 : x1;
            B1.uu[0] = hh ? x6 : u4;  B1.uu[1] = hh ? x7 : u5;
            B1.uu[2] = hh ? u6 : x4;  B1.uu[3] = hh ? u7 : x5;
            // O^T(128d x 32q) += V^T_half @ P^T
            __builtin_amdgcn_s_setprio(1);
#define PV_STEP(DT, OACC) { \
    int vrow = DT*32 + l5; \
    bh8_t vf0 = *(const bh8_t*)(vb + vrow*64 + (((qq*4 + hh) ^ (vrow & 7))<<3)); \
    OACC = __builtin_amdgcn_mfma_f32_32x32x16_bf16(vf0, B0.v, OACC, 0, 0, 0); \
    bh8_t vf1 = *(const bh8_t*)(vb + vrow*64 + (((qq*4 + 2 + hh) ^ (vrow & 7))<<3)); \
    OACC = __builtin_amdgcn_mfma_f32_32x32x16_bf16(vf1, B1.v, OACC, 0, 0, 0); }
            PV_STEP(0, o0) PV_STEP(1, o1) PV_STEP(2, o2) PV_STEP(3, o3)
#undef PV_STEP
            __builtin_amdgcn_s_setprio(0);
        }
        asm volatile("s_waitcnt lgkmcnt(0)" ::: "memory");
        __builtin_amdgcn_s_barrier();
        asm volatile("" ::: "memory");
    }

    // ---- 2-way stream merge per qsub (LDS reuse), then epilogue ----
    f32x16_t oA[4] = {o0, o1, o2, o3};
    float* OB = (float*)SMEM;
    float* ML = (float*)(SMEM + 32768);
    unsigned short* YS = (unsigned short*)(SMEM + 33280);
    if (qq != 0) {
        float* obuf = OB + (size_t)qsub * 4096;
        #pragma unroll
        for (int dt = 0; dt < 4; dt++)
            #pragma unroll
            for (int g = 0; g < 4; g++) {
                f32x4_t v4;
                #pragma unroll
                for (int e = 0; e < 4; e++) v4[e] = oA[dt][g*4+e];
                int ch = (dt*4 + g) ^ (l & 7);
                *(f32x4_t*)(obuf + l*64 + ch*4) = v4;
            }
        if (hh == 0) {
            ML[(qsub*32 + l5)*2]     = mrun;
            ML[(qsub*32 + l5)*2 + 1] = lrun;
        }
    }
    __syncthreads();
    if (qq == 0) {
        float mb = ML[(qsub*32 + l5)*2];
        float lb = ML[(qsub*32 + l5)*2 + 1];
        float mN = fmaxf(mrun, mb);
        float fa = __builtin_amdgcn_exp2f(mrun - mN), fb = __builtin_amdgcn_exp2f(mb - mN);
        const float* obuf = OB + (size_t)qsub * 4096;
        #pragma unroll
        for (int dt = 0; dt < 4; dt++)
            #pragma unroll
            for (int g = 0; g < 4; g++) {
                int ch = (dt*4 + g) ^ (l & 7);
                f32x4_t v4 = *(const f32x4_t*)(obuf + l*64 + ch*4);
                #pragma unroll
                for (int e = 0; e < 4; e++)
                    oA[dt][g*4+e] = oA[dt][g*4+e]*fa + v4[e]*fb;
            }
        lrun = lrun*fa + lb*fb;
        float gv = gate[((size_t)b*T_ + (size_t)qg)*H_ + h];
        float inv = gv / lrun;
        #pragma unroll
        for (int dt = 0; dt < 4; dt++)
            #pragma unroll
            for (int g = 0; g < 4; g++) {
                unsigned short pk4[4];
                #pragma unroll
                for (int e = 0; e < 4; e++) pk4[e] = bf16r(oA[dt][g*4+e] * inv);
                int ch = (dt*4 + g) ^ (qrow & 7);
                *(us4_t*)(YS + (size_t)qrow*128 + ch*8 + hh*4) = *(const us4_t*)pk4;
            }
    }
    __syncthreads();
    #pragma unroll
    for (int i = 0; i < 4; i++) {
        int idx = tid + i*256;
        int r = idx >> 4, scn = idx & 15;
        int lcn = scn ^ (r & 7);
        int4 v = *(const int4*)(YS + (size_t)r*128 + scn*8);
        *(int4*)(Yb + (size_t)(b*T_ + qt*64 + r)*DIM_ + h*HD_ + lcn*8) = v;
    }
#undef STAGE
}

extern "C" void kernel_launch(void* const* d_in, const int* in_sizes, int n_in,
                              void* d_out, int out_size, void* d_ws, size_t ws_size,
                              hipStream_t stream) {
    const float* x    = (const float*)d_in[0];
    const float* ve   = (const float*)d_in[1];
    const float* lam  = (const float*)d_in[2];
    const float* cosb = (const float*)d_in[3];
    const float* sinb = (const float*)d_in[4];
    const float* qkvo = (const float*)d_in[5];
    const float* gw   = (const float*)d_in[6];

    char* ws = (char*)d_ws;
    float* scales  = (float*)ws;
    float* partial = scales + 16;
    unsigned short* WQb  = (unsigned short*)(ws + (1<<13));           // 8 MB
    unsigned short* XQb  = WQb + (size_t)4*DIM_*DIM_;                 // 8 MB
    unsigned short* QKVb = XQb + (size_t)BT_*DIM_;                    // 24 MB (later: Yb)
    float* GT = (float*)(QKVb + (size_t)BT_*E3_);                     // 128 KB
    unsigned short* Qb = (unsigned short*)(GT + (size_t)BT_*H_);      // 8 MB
    unsigned short* Kb = Qb + (size_t)B_*H_*T_*HD_;                   // 8 MB
    unsigned short* VT = Kb + (size_t)B_*H_*T_*HD_;                   // 8 MB
    unsigned short* Yb = QKVb;                                        // reuse (dead after qkv_post_tv)

    absmean1_kernel<<<1024, 256, 0, stream>>>(qkvo, partial);
    absmean2_kernel<<<4, 256, 0, stream>>>(partial, scales);
    quant_w_kernel<<<(4*DIM_*DIM_)/(256*8), 256, 0, stream>>>(qkvo, scales, WQb);
    quant_x_gate_kernel<<<BT_, 256, 0, stream>>>(x, gw, XQb, GT);
    gemm_bf16_kernel<4, true><<<dim3(E3_/128, BT_/128), 256, 0, stream>>>(XQb, WQb, scales, 0, QKVb, BT_, E3_, DIM_);
    qkv_post_tv_kernel<<<BT_ + 1024, 256, 0, stream>>>(QKVb, ve, lam, cosb, sinb, Qb, Kb, VT);
    attn_kernel<<<512, 256, 0, stream>>>(Qb, Kb, VT, GT, Yb);
    gemm_bf16_kernel<2, false><<<dim3(DIM_/128, BT_/64), 256, 0, stream>>>(Yb, WQb + (size_t)3*DIM_*DIM_, scales, 3,
                                                                           (float*)d_out, BT_, DIM_, DIM_);
}

// Round 14
// 136.459 us; speedup vs baseline: 1.6858x; 1.0338x over previous
//
#include <hip/hip_runtime.h>
#include <hip/hip_bf16.h>
#include <cstddef>
#include <cstdint>

#define B_    2
#define T_    2048
#define DIM_  1024
#define H_    8
#define HD_   128
#define BT_   (B_*T_)           // 4096
#define E3_   (3*H_*HD_)        // 3072
#define F32_EPS_ 1.1920929e-07f
#define QSC_  0.17312340490667562f   // 0.12 * log2(e): softmax runs in log2 domain

typedef __attribute__((ext_vector_type(8))) short bh8_t;
typedef __attribute__((ext_vector_type(4))) float f32x4_t;
typedef __attribute__((ext_vector_type(16))) float f32x16_t;
typedef __attribute__((ext_vector_type(4))) unsigned short us4_t;

__device__ inline unsigned short bf16r(float f) {
    unsigned u = __builtin_bit_cast(unsigned, f);
    u = (u + 0x7fffu + ((u >> 16) & 1u)) >> 16;
    return (unsigned short)u;
}
__device__ inline float b2f(unsigned short u) {
    return __builtin_bit_cast(float, (unsigned)u << 16);
}
__device__ inline unsigned cvtpk(float a, float b) {
    unsigned r;
    asm("v_cvt_pk_bf16_f32 %0, %1, %2" : "=v"(r) : "v"(a), "v"(b));
    return r;
}
__device__ inline void gl16(const unsigned short* g, unsigned short* l) {
    __builtin_amdgcn_global_load_lds((const __attribute__((address_space(1))) void*)g,
                                     (__attribute__((address_space(3))) void*)l, 16, 0, 0);
}

// ---------------- K1: per-chunk |w| partial sums ----------------
__global__ __launch_bounds__(256) void absmean1_kernel(const float* __restrict__ w, float* __restrict__ partial) {
    int blk = blockIdx.x;
    size_t off = (size_t)blk * 4096;
    __shared__ float red[256];
    int tid = threadIdx.x;
    float acc = 0.f;
    const float* p = w + off + tid*16;
    #pragma unroll
    for (int j = 0; j < 4; j++) {
        float4 v = *(const float4*)(p + j*4);
        acc += fabsf(v.x) + fabsf(v.y) + fabsf(v.z) + fabsf(v.w);
    }
    red[tid] = acc; __syncthreads();
    for (int s = 128; s > 0; s >>= 1) { if (tid < s) red[tid] += red[tid+s]; __syncthreads(); }
    if (tid == 0) partial[blk] = red[0];
}

// ---------------- K2: merged quant_w (0..2047) + quant_x_gate (2048..6143) + scales write (6144..6147) ----------------
// quant_w blocks re-derive their matrix scale with the SAME LDS-tree order as the old absmean2
// (bit-identical scales); scales[] array written by the 4 tail blocks for the GEMM epilogues.
__global__ __launch_bounds__(256) void prep_kernel(const float* __restrict__ w, const float* __restrict__ partial,
                                                   const float* __restrict__ x, const float* __restrict__ gw,
                                                   unsigned short* __restrict__ wq,
                                                   unsigned short* __restrict__ xqb, float* __restrict__ gate,
                                                   float* __restrict__ scales) {
    __shared__ float red[256];
    __shared__ float x12[12];
    int bid = blockIdx.x;
    int tid = threadIdx.x;
    if (bid < 2048) {
        int m = bid >> 9;                       // 512 blocks per matrix
        red[tid] = partial[m*256 + tid]; __syncthreads();
        for (int s = 128; s > 0; s >>= 1) { if (tid < s) red[tid] += red[tid+s]; __syncthreads(); }
        float sm = fmaxf(red[0] / (float)(DIM_*DIM_), 1e-5f);
        float inv = 1.f / sm;
        int base = (bid * 256 + tid) * 8;
        unsigned short out[8];
        float4 v0 = *(const float4*)(w + base);
        float4 v1 = *(const float4*)(w + base + 4);
        float t[8] = {v0.x, v0.y, v0.z, v0.w, v1.x, v1.y, v1.z, v1.w};
        #pragma unroll
        for (int j = 0; j < 8; j++) {
            float r = rintf(t[j] * inv);
            r = fminf(1.f, fmaxf(-1.f, r));
            out[j] = (r == 0.f) ? 0 : (r > 0.f ? 0x3F80 : 0xBF80);
        }
        *(int4*)(wq + base) = *(const int4*)out;
    } else if (bid < 2048 + BT_) {
        int row = bid - 2048;
        const float* xr = x + (size_t)row * DIM_;
        unsigned short* qr = xqb + (size_t)row * DIM_;
        int w_ = tid >> 6, l = tid & 63;
        float v[4];
        float mn = 1e30f, mx = -1e30f;
        #pragma unroll
        for (int i = 0; i < 4; i++) {
            v[i] = xr[i*256 + tid];
            mn = fminf(mn, v[i]); mx = fmaxf(mx, v[i]);
        }
        #pragma unroll
        for (int off = 1; off < 64; off <<= 1) {
            mn = fminf(mn, __shfl_xor(mn, off));
            mx = fmaxf(mx, __shfl_xor(mx, off));
        }
        if (l == 0) { red[w_] = mn; red[4 + w_] = mx; }
        __syncthreads();
        mn = fminf(fminf(red[0], red[1]), fminf(red[2], red[3]));
        mx = fmaxf(fmaxf(red[4], red[5]), fmaxf(red[6], red[7]));
        float p = fmaxf(mx, 1e-5f);
        float n = fminf(mn, -1e-5f);
        #pragma unroll
        for (int i = 0; i < 4; i++) {
            int gi = i*256 + tid;
            float xv = v[i];
            float sc = (xv >= 0.f) ? p : n;
            float q = rintf(xv / sc * 127.f) / 127.f * sc;
            qr[gi] = bf16r(q);
            if (gi < 12) x12[gi] = q;
        }
        __syncthreads();
        if (tid < H_) {
            float acc = 0.f;
            #pragma unroll
            for (int f = 0; f < 12; f++) acc += x12[f] * gw[tid*12 + f];
            gate[(size_t)row * H_ + tid] = 1.f / (1.f + expf(-acc));
        }
    } else {
        int m = bid - (2048 + BT_);             // 0..3
        red[tid] = partial[m*256 + tid]; __syncthreads();
        for (int s = 128; s > 0; s >>= 1) { if (tid < s) red[tid] += red[tid+s]; __syncthreads(); }
        if (tid == 0) scales[m] = fmaxf(red[0] / (float)(DIM_*DIM_), 1e-5f);
    }
}

// ---------------- bf16 MFMA GEMM. BM = MT*32, BN = 128, BK = 64. OBF: bf16 output ----------------
template<int MT, bool OBF>
__global__ __launch_bounds__(256) void gemm_bf16_kernel(const unsigned short* __restrict__ A,
                                                        const unsigned short* __restrict__ Bm,
                                                        const float* __restrict__ sw, int sbase,
                                                        void* __restrict__ Cv, int M, int N, int K) {
    __shared__ __align__(16) unsigned short As[MT*32*64];
    __shared__ __align__(16) unsigned short Bs[128*64];
    int bm = blockIdx.y * (MT*32), bn = blockIdx.x * 128;
    int tid = threadIdx.x;
    int w = tid >> 6, l = tid & 63;
    int wr = w >> 1, wc = w & 1;
    int lg = l >> 4, lq = l & 15;
    f32x4_t acc[MT][4];
    #pragma unroll
    for (int mt = 0; mt < MT; mt++)
        #pragma unroll
        for (int nt = 0; nt < 4; nt++) acc[mt][nt] = (f32x4_t)0.f;

    for (int k0 = 0; k0 < K; k0 += 64) {
        #pragma unroll
        for (int i = 0; i < MT; i++) {
            int ob = (i*4 + w) << 10;
            int o  = ob + (l << 4);
            int row = o >> 7;
            int lcn = ((o >> 4) & 7) ^ (row & 7);
            gl16(A + (size_t)(bm+row)*K + k0 + lcn*8, (unsigned short*)As + (ob >> 1));
        }
        #pragma unroll
        for (int i = 0; i < 4; i++) {
            int ob = (i*4 + w) << 10;
            int o  = ob + (l << 4);
            int row = o >> 7;
            int lcn = ((o >> 4) & 7) ^ (row & 7);
            gl16(Bm + (size_t)(bn+row)*K + k0 + lcn*8, (unsigned short*)Bs + (ob >> 1));
        }
        __syncthreads();
        #pragma unroll
        for (int kk = 0; kk < 2; kk++) {
            bh8_t af[MT], bf[4];
            #pragma unroll
            for (int mt = 0; mt < MT; mt++) {
                int r = wr*(MT*16) + mt*16 + lq;
                int j = kk*4 + lg;
                af[mt] = *(const bh8_t*)(As + r*64 + (((j ^ (r & 7)))<<3));
            }
            #pragma unroll
            for (int nt = 0; nt < 4; nt++) {
                int r = wc*64 + nt*16 + lq;
                int j = kk*4 + lg;
                bf[nt] = *(const bh8_t*)(Bs + r*64 + (((j ^ (r & 7)))<<3));
            }
            #pragma unroll
            for (int mt = 0; mt < MT; mt++)
                #pragma unroll
                for (int nt = 0; nt < 4; nt++)
                    acc[mt][nt] = __builtin_amdgcn_mfma_f32_16x16x32_bf16(af[mt], bf[nt], acc[mt][nt], 0, 0, 0);
        }
        __syncthreads();
    }
    #pragma unroll
    for (int nt = 0; nt < 4; nt++) {
        int col = bn + wc*64 + nt*16 + lq;
        float s = sw[sbase + (col >> 10)];
        #pragma unroll
        for (int mt = 0; mt < MT; mt++) {
            int row = bm + wr*(MT*16) + mt*16 + lg*4;
            #pragma unroll
            for (int r = 0; r < 4; r++) {
                if constexpr (OBF)
                    ((unsigned short*)Cv)[(size_t)(row + r)*N + col] = bf16r(acc[mt][nt][r] * s);
                else
                    ((float*)Cv)[(size_t)(row + r)*N + col] = acc[mt][nt][r] * s;
            }
        }
    }
}

// ---------------- K5: merged qkv_post (blocks 0..4095) + ve-mix/transpose-V (blocks 4096..5119) ----------------
__global__ __launch_bounds__(256) void qkv_post_tv_kernel(const unsigned short* __restrict__ qkvb,
                                                          const float* __restrict__ ve,
                                                          const float* __restrict__ lam,
                                                          const float* __restrict__ cosb, const float* __restrict__ sinb,
                                                          unsigned short* __restrict__ Qb, unsigned short* __restrict__ Kb,
                                                          unsigned short* __restrict__ VT) {
    __shared__ unsigned short L[64][80];
    int bid = blockIdx.x;
    int tid = threadIdx.x;
    if (bid < BT_) {
        int bt = bid;
        int b = bt >> 11, t = bt & (T_ - 1);
        int w = tid >> 6, l = tid & 63;
        const unsigned short* base = qkvb + (size_t)bt * E3_;
        float cc = cosb[(size_t)t*64 + l], ss = sinb[(size_t)t*64 + l];
        #pragma unroll
        for (int i = 0; i < 4; i++) {
            int part = w*4 + i;                 // 0..15
            const unsigned short* row = base + part*HD_;
            float x1 = b2f(row[l]), x2 = b2f(row[l+64]);
            float ssq = x1*x1 + x2*x2;
            #pragma unroll
            for (int off = 1; off < 64; off <<= 1) ssq += __shfl_xor(ssq, off);
            float rms = 1.0f / sqrtf(ssq / 128.0f + F32_EPS_);
            x1 *= rms; x2 *= rms;
            float o1 = x1*cc + x2*ss;
            float o2 = -x1*ss + x2*cc;
            float mn = fminf(o1, o2), mx = fmaxf(o1, o2);
            #pragma unroll
            for (int off = 1; off < 64; off <<= 1) {
                mn = fminf(mn, __shfl_xor(mn, off));
                mx = fmaxf(mx, __shfl_xor(mx, off));
            }
            float p = fmaxf(mx, 1e-5f);
            float n = fminf(mn, -1e-5f);
            float s1 = (o1 >= 0.f) ? p : n;
            float s2 = (o2 >= 0.f) ? p : n;
            float q1 = rintf(o1 / s1 * 127.f) / 127.f * s1;
            float q2 = rintf(o2 / s2 * 127.f) / 127.f * s2;
            if (part < 8) {
                unsigned short* dst = Qb + ((size_t)(b*H_+part)*T_ + t)*HD_;
                dst[l] = bf16r(QSC_ * q1); dst[l + 64] = bf16r(QSC_ * q2);
            } else {
                unsigned short* dst = Kb + ((size_t)(b*H_+part-8)*T_ + t)*HD_;
                dst[l] = bf16r(q1); dst[l + 64] = bf16r(q2);
            }
        }
    } else {
        int r0 = bid - BT_;                    // 0..1023
        int tt = r0 & 31;
        int dt = (r0 >> 5) & 1;
        int bh = r0 >> 6;
        int b = bh >> 3, h = bh & 7;
        float l0 = lam[0], l1 = lam[1];
        #pragma unroll
        for (int i = 0; i < 2; i++) {
            int c = tid + i*256;
            int r = c >> 3, dc = c & 7;
            size_t bt = (size_t)(b*T_ + tt*64 + r);
            union { int4 v; unsigned short q[8]; } u;
            u.v = *(const int4*)(qkvb + bt*E3_ + (16 + h)*HD_ + dt*64 + dc*8);
            float4 va = *(const float4*)(ve + bt*DIM_ + h*HD_ + dt*64 + dc*8);
            float4 vb = *(const float4*)(ve + bt*DIM_ + h*HD_ + dt*64 + dc*8 + 4);
            float vv[8] = {va.x, va.y, va.z, va.w, vb.x, vb.y, vb.z, vb.w};
            unsigned short mix[8];
            #pragma unroll
            for (int k = 0; k < 8; k++) mix[k] = bf16r(l0*b2f(u.q[k]) + l1*vv[k]);
            *(int4*)(&L[r][dc*8]) = *(const int4*)mix;
        }
        __syncthreads();
        #pragma unroll
        for (int i = 0; i < 2; i++) {
            int c = tid + i*256;
            int r = c >> 3, tc = c & 7;
            unsigned short tmp[8];
            #pragma unroll
            for (int jj = 0; jj < 8; jj++) tmp[jj] = L[tc*8+jj][r];
            *(int4*)(VT + ((size_t)bh*HD_ + dt*64 + r)*T_ + tt*64 + tc*8) = *(const int4*)tmp;
        }
    }
}

// ---------------- K7: flash attention (r6 structure, best measured) ----------------
__global__ __launch_bounds__(256) void attn_kernel(const unsigned short* __restrict__ Qb,
                                                   const unsigned short* __restrict__ Kb,
                                                   const unsigned short* __restrict__ VT,
                                                   const float* __restrict__ gate,
                                                   unsigned short* __restrict__ Yb) {
    __shared__ __align__(16) unsigned char SMEM[65536];   // K[2]:2x16KB | V[2]:2x16KB
    int id = blockIdx.x;
    int bh = id & 15;
    int qi = id >> 4;
    int qt = (qi < 16) ? (31 - qi) : (qi - 16);           // pair big with small per CU
    int b = bh >> 3, h = bh & 7;
    int tid = threadIdx.x;
    int w = tid >> 6, l = tid & 63;
    int qsub = w >> 1, qq = w & 1;
    int hh = l >> 5, l5 = l & 31;
    int qrow = qsub*32 + l5;
    int qg = qt*64 + qrow;

    const unsigned short* Kbase = Kb + (size_t)bh*T_*HD_;
    const unsigned short* Vbase = VT + (size_t)bh*HD_*T_;
    const unsigned short* Qg = Qb + ((size_t)bh*T_ + (size_t)qt*64) * HD_;

    bh8_t qf[8];
    #pragma unroll
    for (int ks = 0; ks < 8; ks++)
        qf[ks] = *(const bh8_t*)(Qg + (size_t)qrow*HD_ + ks*16 + hh*8);

    int nr = qt + 1;

    f32x16_t o0 = (f32x16_t)0.f, o1 = (f32x16_t)0.f, o2 = (f32x16_t)0.f, o3 = (f32x16_t)0.f;
    float mrun = -1e20f, lrun = 0.f;

    // K: 4-bit XOR swizzle (16-chunk rows, 2-way = free); V: 3-bit (8-chunk rows)
#define STAGE(BI, J) { \
    unsigned short* kb_ = (unsigned short*)(SMEM + (BI)*16384); \
    unsigned short* vb_ = (unsigned short*)(SMEM + 32768 + (BI)*16384); \
    _Pragma("unroll") \
    for (int i_ = 0; i_ < 4; i_++) { \
        int ob_ = (i_*4 + w) << 10; \
        int o_  = ob_ + (l << 4); \
        int rk_ = o_ >> 8; \
        int lk_ = ((o_ >> 4) & 15) ^ (rk_ & 15); \
        gl16(Kbase + (size_t)((J)*64 + rk_)*HD_ + lk_*8, kb_ + (ob_ >> 1)); \
        int rv_ = o_ >> 7; \
        int lv_ = ((o_ >> 4) & 7) ^ (rv_ & 7); \
        gl16(Vbase + (size_t)rv_*T_ + (J)*64 + lv_*8, vb_ + (ob_ >> 1)); \
    } }

    STAGE(0, 0);
    for (int j = 0; j < nr; j++) {
        if (j + 1 < nr) {
            STAGE((j+1) & 1, j+1);
            asm volatile("s_waitcnt vmcnt(8)" ::: "memory");
        } else {
            asm volatile("s_waitcnt vmcnt(0)" ::: "memory");
        }
        __builtin_amdgcn_s_barrier();
        asm volatile("" ::: "memory");
        const unsigned short* kb = (const unsigned short*)(SMEM + (j&1)*16384);
        const unsigned short* vb = (const unsigned short*)(SMEM + 32768 + (j&1)*16384);
        int kvb = j*64 + qq*32;
        if (kvb <= qt*64 + qsub*32 + 31) {
            // S^T(32k x 32q) = K_half @ Q^T   (log2 domain: Q pre-scaled by 0.12*log2e)
            f32x16_t s = (f32x16_t)0.f;
            int krow = qq*32 + l5;
            __builtin_amdgcn_s_setprio(1);
            #pragma unroll
            for (int ks = 0; ks < 8; ks++) {
                int c = (ks*2 + hh) ^ (krow & 15);
                bh8_t kf = *(const bh8_t*)(kb + krow*128 + c*8);
                s = __builtin_amdgcn_mfma_f32_32x32x16_bf16(kf, qf[ks], s, 0, 0, 0);
            }
            __builtin_amdgcn_s_setprio(0);
            if (kvb + 31 > qt*64 + qsub*32) {
                #pragma unroll
                for (int r = 0; r < 16; r++) {
                    int key = kvb + (r & 3) + 8*(r >> 2) + 4*hh;
                    if (key > qg) s[r] = -1e30f;
                }
            }
            // online softmax, defer-max THR=8 (P bounded by 2^8)
            float t8[8], t4[4];
            #pragma unroll
            for (int r = 0; r < 8; r++) t8[r] = fmaxf(s[2*r], s[2*r+1]);
            #pragma unroll
            for (int r = 0; r < 4; r++) t4[r] = fmaxf(t8[2*r], t8[2*r+1]);
            float tm = fmaxf(fmaxf(t4[0], t4[1]), fmaxf(t4[2], t4[3]));
            tm = fmaxf(tm, __shfl_xor(tm, 32));
            if (!__all(tm - mrun <= 8.f)) {
                float mnew = fmaxf(mrun, tm);
                float scf = __builtin_amdgcn_exp2f(mrun - mnew);
                lrun *= scf;
                o0 *= scf; o1 *= scf; o2 *= scf; o3 *= scf;
                mrun = mnew;
            }
            float p[16];
            #pragma unroll
            for (int r = 0; r < 16; r++) p[r] = __builtin_amdgcn_exp2f(s[r] - mrun);
            #pragma unroll
            for (int r = 0; r < 8; r++) t8[r] = p[2*r] + p[2*r+1];
            #pragma unroll
            for (int r = 0; r < 4; r++) t4[r] = t8[2*r] + t8[2*r+1];
            float ls = (t4[0] + t4[1]) + (t4[2] + t4[3]);
            ls += __shfl_xor(ls, 32);
            lrun += ls;
            // pack P -> bf16 B-frags (v_cvt_pk) via lane<->lane+32 exchange
            unsigned u0 = cvtpk(p[0], p[1]),   u1 = cvtpk(p[2], p[3]);
            unsigned u2 = cvtpk(p[4], p[5]),   u3 = cvtpk(p[6], p[7]);
            unsigned u4 = cvtpk(p[8], p[9]),   u5 = cvtpk(p[10], p[11]);
            unsigned u6 = cvtpk(p[12], p[13]), u7 = cvtpk(p[14], p[15]);
            unsigned x0 = (unsigned)__shfl_xor((int)u0, 32), x1 = (unsigned)__shfl_xor((int)u1, 32);
            unsigned x2 = (unsigned)__shfl_xor((int)u2, 32), x3 = (unsigned)__shfl_xor((int)u3, 32);
            unsigned x4 = (unsigned)__shfl_xor((int)u4, 32), x5 = (unsigned)__shfl_xor((int)u5, 32);
            unsigned x6 = (unsigned)__shfl_xor((int)u6, 32), x7 = (unsigned)__shfl_xor((int)u7, 32);
            union { bh8_t v; unsigned uu[4]; } B0, B1;
            B0.uu[0] = hh ? x2 : u0;  B0.uu[1] = hh ? x3 : u1;
            B0.uu[2] = hh ? u2 : x0;  B0.uu[3] = hh ? u3 : x1;
            B1.uu[0] = hh ? x6 : u4;  B1.uu[1] = hh ? x7 : u5;
            B1.uu[2] = hh ? u6 : x4;  B1.uu[3] = hh ? u7 : x5;
            // O^T(128d x 32q) += V^T_half @ P^T
            __builtin_amdgcn_s_setprio(1);
#define PV_STEP(DT, OACC) { \
    int vrow = DT*32 + l5; \
    bh8_t vf0 = *(const bh8_t*)(vb + vrow*64 + (((qq*4 + hh) ^ (vrow & 7))<<3)); \
    OACC = __builtin_amdgcn_mfma_f32_32x32x16_bf16(vf0, B0.v, OACC, 0, 0, 0); \
    bh8_t vf1 = *(const bh8_t*)(vb + vrow*64 + (((qq*4 + 2 + hh) ^ (vrow & 7))<<3)); \
    OACC = __builtin_amdgcn_mfma_f32_32x32x16_bf16(vf1, B1.v, OACC, 0, 0, 0); }
            PV_STEP(0, o0) PV_STEP(1, o1) PV_STEP(2, o2) PV_STEP(3, o3)
#undef PV_STEP
            __builtin_amdgcn_s_setprio(0);
        }
        asm volatile("s_waitcnt lgkmcnt(0)" ::: "memory");
        __builtin_amdgcn_s_barrier();
        asm volatile("" ::: "memory");
    }

    // ---- 2-way stream merge per qsub (LDS reuse), then epilogue ----
    f32x16_t oA[4] = {o0, o1, o2, o3};
    float* OB = (float*)SMEM;
    float* ML = (float*)(SMEM + 32768);
    unsigned short* YS = (unsigned short*)(SMEM + 33280);
    if (qq != 0) {
        float* obuf = OB + (size_t)qsub * 4096;
        #pragma unroll
        for (int dt = 0; dt < 4; dt++)
            #pragma unroll
            for (int g = 0; g < 4; g++) {
                f32x4_t v4;
                #pragma unroll
                for (int e = 0; e < 4; e++) v4[e] = oA[dt][g*4+e];
                int ch = (dt*4 + g) ^ (l & 7);
                *(f32x4_t*)(obuf + l*64 + ch*4) = v4;
            }
        if (hh == 0) {
            ML[(qsub*32 + l5)*2]     = mrun;
            ML[(qsub*32 + l5)*2 + 1] = lrun;
        }
    }
    __syncthreads();
    if (qq == 0) {
        float mb = ML[(qsub*32 + l5)*2];
        float lb = ML[(qsub*32 + l5)*2 + 1];
        float mN = fmaxf(mrun, mb);
        float fa = __builtin_amdgcn_exp2f(mrun - mN), fb = __builtin_amdgcn_exp2f(mb - mN);
        const float* obuf = OB + (size_t)qsub * 4096;
        #pragma unroll
        for (int dt = 0; dt < 4; dt++)
            #pragma unroll
            for (int g = 0; g < 4; g++) {
                int ch = (dt*4 + g) ^ (l & 7);
                f32x4_t v4 = *(const f32x4_t*)(obuf + l*64 + ch*4);
                #pragma unroll
                for (int e = 0; e < 4; e++)
                    oA[dt][g*4+e] = oA[dt][g*4+e]*fa + v4[e]*fb;
            }
        lrun = lrun*fa + lb*fb;
        float gv = gate[((size_t)b*T_ + (size_t)qg)*H_ + h];
        float inv = gv / lrun;
        #pragma unroll
        for (int dt = 0; dt < 4; dt++)
            #pragma unroll
            for (int g = 0; g < 4; g++) {
                unsigned short pk4[4];
                #pragma unroll
                for (int e = 0; e < 4; e++) pk4[e] = bf16r(oA[dt][g*4+e] * inv);
                int ch = (dt*4 + g) ^ (qrow & 7);
                *(us4_t*)(YS + (size_t)qrow*128 + ch*8 + hh*4) = *(const us4_t*)pk4;
            }
    }
    __syncthreads();
    #pragma unroll
    for (int i = 0; i < 4; i++) {
        int idx = tid + i*256;
        int r = idx >> 4, scn = idx & 15;
        int lcn = scn ^ (r & 7);
        int4 v = *(const int4*)(YS + (size_t)r*128 + scn*8);
        *(int4*)(Yb + (size_t)(b*T_ + qt*64 + r)*DIM_ + h*HD_ + lcn*8) = v;
    }
#undef STAGE
}

extern "C" void kernel_launch(void* const* d_in, const int* in_sizes, int n_in,
                              void* d_out, int out_size, void* d_ws, size_t ws_size,
                              hipStream_t stream) {
    const float* x    = (const float*)d_in[0];
    const float* ve   = (const float*)d_in[1];
    const float* lam  = (const float*)d_in[2];
    const float* cosb = (const float*)d_in[3];
    const float* sinb = (const float*)d_in[4];
    const float* qkvo = (const float*)d_in[5];
    const float* gw   = (const float*)d_in[6];

    char* ws = (char*)d_ws;
    float* scales  = (float*)ws;
    float* partial = scales + 16;
    unsigned short* WQb  = (unsigned short*)(ws + (1<<13));           // 8 MB
    unsigned short* XQb  = WQb + (size_t)4*DIM_*DIM_;                 // 8 MB
    unsigned short* QKVb = XQb + (size_t)BT_*DIM_;                    // 24 MB (later: Yb)
    float* GT = (float*)(QKVb + (size_t)BT_*E3_);                     // 128 KB
    unsigned short* Qb = (unsigned short*)(GT + (size_t)BT_*H_);      // 8 MB
    unsigned short* Kb = Qb + (size_t)B_*H_*T_*HD_;                   // 8 MB
    unsigned short* VT = Kb + (size_t)B_*H_*T_*HD_;                   // 8 MB
    unsigned short* Yb = QKVb;                                        // reuse (dead after qkv_post_tv)

    absmean1_kernel<<<1024, 256, 0, stream>>>(qkvo, partial);
    prep_kernel<<<2048 + BT_ + 4, 256, 0, stream>>>(qkvo, partial, x, gw, WQb, XQb, GT, scales);
    gemm_bf16_kernel<4, true><<<dim3(E3_/128, BT_/128), 256, 0, stream>>>(XQb, WQb, scales, 0, QKVb, BT_, E3_, DIM_);
    qkv_post_tv_kernel<<<BT_ + 1024, 256, 0, stream>>>(QKVb, ve, lam, cosb, sinb, Qb, Kb, VT);
    attn_kernel<<<512, 256, 0, stream>>>(Qb, Kb, VT, GT, Yb);
    gemm_bf16_kernel<2, false><<<dim3(DIM_/128, BT_/64), 256, 0, stream>>>(Yb, WQb + (size_t)3*DIM_*DIM_, scales, 3,
                                                                           (float*)d_out, BT_, DIM_, DIM_);
}